// Round 3
// baseline (842.668 us; speedup 1.0000x reference)
//
#include <hip/hip_runtime.h>
#include <hip/hip_fp16.h>

#define NV 50000
#define EV 800000
#define INF 128
#define HD 64
#define KNEG 5
#define NB ((NV + 1023) / 1024)   // 49 scan blocks

// ------- embed + hist fused, v2: W-in-VGPR, wave-private dbuf ---------
__global__ __launch_bounds__(256) void embed_hist_kernel(
    const float* __restrict__ feat, const float* __restrict__ W,
    const float* __restrict__ b, float* __restrict__ h,
    const int* __restrict__ dst, int* __restrict__ deg) {
  __shared__ float sF[4][2][512];   // wave x buf x (4 rows * 128) = 16 KB
  const int lane = threadIdx.x & 63;
  const int wave = threadIdx.x >> 6;
  float Wreg[INF];
#pragma unroll
  for (int k = 0; k < INF; k++) Wreg[k] = W[k * HD + lane];
  const float bias = b[lane];
  const int nwaves = gridDim.x * 4;
  const int wid = blockIdx.x * 4 + wave;   // wave-uniform
  const int ngroups = NV / 4;              // 12500 exactly

  int buf = 0;
  int g = wid;
  if (g < ngroups) {
    const float4* gp = (const float4*)(feat + (size_t)g * 512);
    const float4 a0 = gp[lane];
    const float4 a1 = gp[lane + 64];
    ((float4*)sF[wave][0])[lane] = a0;
    ((float4*)sF[wave][0])[lane + 64] = a1;
  }
  for (; g < ngroups; g += nwaves) {
    const int gn = g + nwaves;
    float4 b0, b1;
    if (gn < ngroups) {                    // wave-uniform guard
      const float4* gp = (const float4*)(feat + (size_t)gn * 512);
      b0 = gp[lane];
      b1 = gp[lane + 64];
    }
    float acc0 = bias, acc1 = bias, acc2 = bias, acc3 = bias;
    const float4* F = (const float4*)sF[wave][buf];
#pragma unroll
    for (int k4 = 0; k4 < 32; k4++) {
      const float4 x0 = F[k4];
      const float4 x1 = F[k4 + 32];
      const float4 x2 = F[k4 + 64];
      const float4 x3 = F[k4 + 96];
      const float w0 = Wreg[4 * k4 + 0];
      const float w1 = Wreg[4 * k4 + 1];
      const float w2 = Wreg[4 * k4 + 2];
      const float w3 = Wreg[4 * k4 + 3];
      acc0 = fmaf(x0.x, w0, acc0); acc0 = fmaf(x0.y, w1, acc0);
      acc0 = fmaf(x0.z, w2, acc0); acc0 = fmaf(x0.w, w3, acc0);
      acc1 = fmaf(x1.x, w0, acc1); acc1 = fmaf(x1.y, w1, acc1);
      acc1 = fmaf(x1.z, w2, acc1); acc1 = fmaf(x1.w, w3, acc1);
      acc2 = fmaf(x2.x, w0, acc2); acc2 = fmaf(x2.y, w1, acc2);
      acc2 = fmaf(x2.z, w2, acc2); acc2 = fmaf(x2.w, w3, acc2);
      acc3 = fmaf(x3.x, w0, acc3); acc3 = fmaf(x3.y, w1, acc3);
      acc3 = fmaf(x3.z, w2, acc3); acc3 = fmaf(x3.w, w3, acc3);
    }
    float* hpo = h + (size_t)g * 256 + lane;
    hpo[0] = acc0;
    hpo[64] = acc1;
    hpo[128] = acc2;
    hpo[192] = acc3;
    if (gn < ngroups) {
      ((float4*)sF[wave][buf ^ 1])[lane] = b0;
      ((float4*)sF[wave][buf ^ 1])[lane + 64] = b1;
      buf ^= 1;
    }
  }
  for (int e = blockIdx.x * 256 + threadIdx.x; e < EV; e += gridDim.x * 256)
    atomicAdd(&deg[dst[e]], 1);
}

// ------- parallel scan, pass 1 ----------------------------------------
__global__ __launch_bounds__(1024) void scan_part_kernel(
    const int* __restrict__ deg, int* __restrict__ off,
    int* __restrict__ bsum) {
  __shared__ int wsum[16];
  const int tid = threadIdx.x;
  const int lane = tid & 63;
  const int w = tid >> 6;
  const int i = blockIdx.x * 1024 + tid;
  const int v = (i < NV) ? deg[i] : 0;
  int s = v;
#pragma unroll
  for (int ofs = 1; ofs < 64; ofs <<= 1) {
    int x = __shfl_up(s, ofs, 64);
    if (lane >= ofs) s += x;
  }
  if (lane == 63) wsum[w] = s;
  __syncthreads();
  if (w == 0) {
    int t2 = (lane < 16) ? wsum[lane] : 0;
#pragma unroll
    for (int ofs = 1; ofs < 16; ofs <<= 1) {
      int x = __shfl_up(t2, ofs, 64);
      if (lane >= ofs) t2 += x;
    }
    if (lane < 16) wsum[lane] = t2;
  }
  __syncthreads();
  const int base = (w > 0) ? wsum[w - 1] : 0;
  if (i < NV) off[i] = base + s - v;
  if (tid == 0) bsum[blockIdx.x] = wsum[15];
}

// ------- parallel scan, pass 2 ----------------------------------------
__global__ __launch_bounds__(1024) void scan_fix_kernel(
    const int* __restrict__ bsum, int* __restrict__ off,
    int* __restrict__ cursor) {
  __shared__ int sbase, stot;
  const int tid = threadIdx.x;
  const int b = blockIdx.x;
  if (tid == 0) {
    int acc = 0, tot = 0;
    for (int j = 0; j < NB; j++) {
      const int x = bsum[j];
      if (j < b) acc += x;
      tot += x;
    }
    sbase = acc;
    stot = tot;
  }
  __syncthreads();
  const int i = b * 1024 + tid;
  if (i < NV) {
    const int o = off[i] + sbase;
    off[i] = o;
    cursor[i] = o;
  }
  if (b == NB - 1 && tid == 0) off[NV] = stot;
}

// ------- CSR perm -----------------------------------------------------
__global__ __launch_bounds__(256) void perm_kernel(
    const int* __restrict__ src, const int* __restrict__ dst,
    int* __restrict__ cursor, int* __restrict__ gsrc) {
  const int e = blockIdx.x * 256 + threadIdx.x;
  if (e < EV) {
    const int pos = atomicAdd(&cursor[dst[e]], 1);
    gsrc[pos] = src[e];
  }
}

// ------- fused aggregate + combine, v4: one group/wave, fast path -----
// Slot s = lane>>4 owns node n0+s with 16 lanes (q = lane&15). Gather:
// batches of 16 edges per slot; blocks fully below the wave-min degree
// run unmasked (no cmp/cndmask); tail blocks masked. Combine: lane f
// holds Ws[:,f], Wd[:,f] in 128 VGPRs; rows broadcast from wave-private
// LDS (no barriers anywhere).
__global__ __launch_bounds__(256, 4) void aggcomb_kernel(
    const float* __restrict__ hin, float* __restrict__ hout,
    const int* __restrict__ gsrc, const int* __restrict__ off,
    const float* __restrict__ wconv, const float* __restrict__ cb,
    const float* __restrict__ gamma, const float* __restrict__ beta,
    const float* __restrict__ mean, const float* __restrict__ var) {
  __shared__ float sS1[4][4][HD];   // wave x slot x row  (4 KB)
  __shared__ float sH[4][4][HD];    // wave x slot x own-h (4 KB)
  const int wave = threadIdx.x >> 6;
  const int lane = threadIdx.x & 63;
  const int sub = lane >> 4;   // node slot 0..3
  const int q = lane & 15;     // float4 slot within row
  const int f = lane;          // output feature in combine phase
  float Wsr[HD], Wdr[HD];
#pragma unroll
  for (int k = 0; k < HD; k++) Wsr[k] = wconv[k * HD + f];
#pragma unroll
  for (int k = 0; k < HD; k++) Wdr[k] = wconv[(HD + k) * HD + f];
  const float cbf = cb[f];
  const float gf = gamma[f];
  const float btf = beta[f];
  const float mf = mean[f];
  const float inv = rsqrtf(var[f] + 1e-3f);
  const float4* hp = (const float4*)hin;
  const int wid = blockIdx.x * 4 + wave;
  const int nw = gridDim.x * 4;
  const int ngroups = NV / 4;            // 12500 exactly
  for (int g = wid; g < ngroups; g += nw) {
    const int n0 = g * 4;
    const int n = n0 + sub;              // this slot's node
    const int j0 = off[n];
    const int deg = off[n + 1] - j0;
    int dm = deg, dmn = deg;             // wave max / min degree
    {
      int x = __shfl_xor(dm, 16, 64);
      dm = max(dm, x); dmn = min(dmn, __shfl_xor(dmn, 16, 64));
      x = __shfl_xor(dm, 32, 64);
      dm = max(dm, x); dmn = min(dmn, __shfl_xor(dmn, 32, 64));
    }
    const float4 hrow = hp[(size_t)n * 16 + q];   // own row fragment
    float4 acc = make_float4(0.f, 0.f, 0.f, 0.f);
    int base = 0;
    for (; base + 16 <= dmn; base += 16) {        // full blocks: no mask
      const int eid = gsrc[j0 + base + q];
#pragma unroll
      for (int i = 0; i < 16; i++) {
        const int a = __shfl(eid, (sub << 4) | i, 64);
        const float4 v = hp[(size_t)a * 16 + q];
        acc.x += v.x; acc.y += v.y; acc.z += v.z; acc.w += v.w;
      }
    }
    for (; base < dm; base += 16) {               // masked tail blocks
      const int e = base + q;
      const int eid = (e < deg) ? gsrc[j0 + e] : -1;
#pragma unroll
      for (int i = 0; i < 16; i++) {
        const int a = __shfl(eid, (sub << 4) | i, 64);
        const float4 v = hp[(size_t)max(a, 0) * 16 + q];
        const float msk = (a >= 0) ? 1.f : 0.f;
        acc.x = fmaf(v.x, msk, acc.x);
        acc.y = fmaf(v.y, msk, acc.y);
        acc.z = fmaf(v.z, msk, acc.z);
        acc.w = fmaf(v.w, msk, acc.w);
      }
    }
    // hand-off via wave-private LDS (in-order DS pipe; no barrier)
    ((float4*)sS1[wave][sub])[q] = acc;
    ((float4*)sH[wave][sub])[q] = hrow;
#pragma unroll
    for (int m4 = 0; m4 < 4; m4++) {
      const float4* s1p = (const float4*)sS1[wave][m4];
      const float4* hq = (const float4*)sH[wave][m4];
      float a1a = 0.f, a1b = 0.f, a2a = 0.f, a2b = 0.f;
#pragma unroll
      for (int k4 = 0; k4 < 16; k4++) {
        const float4 sv = s1p[k4];       // uniform addr -> broadcast
        const float4 hv = hq[k4];
        a1a = fmaf(sv.x, Wsr[4 * k4 + 0], a1a);
        a1b = fmaf(sv.y, Wsr[4 * k4 + 1], a1b);
        a1a = fmaf(sv.z, Wsr[4 * k4 + 2], a1a);
        a1b = fmaf(sv.w, Wsr[4 * k4 + 3], a1b);
        a2a = fmaf(hv.x, Wdr[4 * k4 + 0], a2a);
        a2b = fmaf(hv.y, Wdr[4 * k4 + 1], a2b);
        a2a = fmaf(hv.z, Wdr[4 * k4 + 2], a2a);
        a2b = fmaf(hv.w, Wdr[4 * k4 + 3], a2b);
      }
      const float a1 = a1a + a1b;
      const float a2 = a2a + a2b;
      const float hvf = sH[wave][m4][f];          // conflict-free b32
      const float d = (float)__shfl(deg, m4 << 4, 64);
      const float agg = a1 + d * a2 + d * cbf;
      const float sig = 1.f / (1.f + __expf(-agg));
      const float sp = fmaxf(hvf, 0.f) + log1pf(__expf(-fabsf(hvf)));
      float x = sig + sp;
      x = gf * (x - mf) * inv + btf;
      hout[(size_t)(n0 + m4) * HD + f] = fmaxf(x, 0.f);
    }
  }
}

// ------- convert h (fp32) -> hh (fp16, RNE) ---------------------------
__global__ __launch_bounds__(256) void convert_kernel(
    const float* __restrict__ h, __half* __restrict__ hh) {
  const int i = blockIdx.x * 256 + threadIdx.x;
  const int idx = i * 4;
  if (idx < NV * HD) {
    const float4 v = *(const float4*)(h + idx);
    __half2* o = (__half2*)(hh + idx);
    o[0] = __floats2half2_rn(v.x, v.y);
    o[1] = __floats2half2_rn(v.z, v.w);
  }
}

// ------- scores: 8 lanes/edge, fp16 rows (128 B each) -----------------
__global__ __launch_bounds__(256) void score_kernel(
    const __half* __restrict__ hh, const int* __restrict__ src,
    const int* __restrict__ dst, const int* __restrict__ neg_dst,
    const float* __restrict__ wrel, float* __restrict__ out) {
  const int tid = blockIdx.x * 256 + threadIdx.x;
  const int e = tid >> 3;
  const int q = tid & 7;
  if (e >= EV) return;
  const float4 w0 = ((const float4*)wrel)[2 * q];
  const float4 w1 = ((const float4*)wrel)[2 * q + 1];
  const int s = src[e];
  const int d = dst[e];
  int nd[KNEG];
#pragma unroll
  for (int r = 0; r < KNEG; r++) nd[r] = neg_dst[e * KNEG + r];

  const uint4* hp = (const uint4*)hh;
  const uint4 sv = hp[(size_t)s * 8 + q];
  const uint4 dv = hp[(size_t)d * 8 + q];
  uint4 nv[KNEG];
#pragma unroll
  for (int r = 0; r < KNEG; r++) nv[r] = hp[(size_t)nd[r] * 8 + q];

#define FLO(u) __half2float(__low2half(*(const __half2*)&(u)))
#define FHI(u) __half2float(__high2half(*(const __half2*)&(u)))
  const float a0 = FLO(sv.x) * w0.x, a1 = FHI(sv.x) * w0.y;
  const float a2 = FLO(sv.y) * w0.z, a3 = FHI(sv.y) * w0.w;
  const float a4 = FLO(sv.z) * w1.x, a5 = FHI(sv.z) * w1.y;
  const float a6 = FLO(sv.w) * w1.z, a7 = FHI(sv.w) * w1.w;

  float p = a0 * FLO(dv.x) + a1 * FHI(dv.x) + a2 * FLO(dv.y) + a3 * FHI(dv.y)
          + a4 * FLO(dv.z) + a5 * FHI(dv.z) + a6 * FLO(dv.w) + a7 * FHI(dv.w);
#pragma unroll
  for (int m = 4; m; m >>= 1) p += __shfl_xor(p, m, 64);
  if (q == 0) out[e] = p;

#pragma unroll
  for (int r = 0; r < KNEG; r++) {
    const uint4 v = nv[r];
    float pn = a0 * FLO(v.x) + a1 * FHI(v.x) + a2 * FLO(v.y) + a3 * FHI(v.y)
             + a4 * FLO(v.z) + a5 * FHI(v.z) + a6 * FLO(v.w) + a7 * FHI(v.w);
#pragma unroll
    for (int m = 4; m; m >>= 1) pn += __shfl_xor(pn, m, 64);
    if (q == 0) out[(size_t)EV + (size_t)e * KNEG + r] = pn;
  }
#undef FLO
#undef FHI
}

extern "C" void kernel_launch(void* const* d_in, const int* in_sizes, int n_in,
                              void* d_out, int out_size, void* d_ws, size_t ws_size,
                              hipStream_t stream) {
  const float* node_feat = (const float*)d_in[0];
  const float* emb_w     = (const float*)d_in[1];
  const float* emb_b     = (const float*)d_in[2];
  const float* conv_w    = (const float*)d_in[3];
  const float* conv_b    = (const float*)d_in[4];
  const float* bn_gamma  = (const float*)d_in[5];
  const float* bn_beta   = (const float*)d_in[6];
  const float* bn_mean   = (const float*)d_in[7];
  const float* bn_var    = (const float*)d_in[8];
  const float* w_rel     = (const float*)d_in[9];
  const int*   src       = (const int*)d_in[10];
  const int*   dst       = (const int*)d_in[11];
  const int*   neg_dst   = (const int*)d_in[12];
  float* out = (float*)d_out;

  float* h   = (float*)d_ws;
  float* h2  = h + (size_t)NV * HD;
  int*   off = (int*)(h2 + (size_t)NV * HD);
  int*   gsrc = off + (NV + 1);
  int*   bsum = gsrc + EV;
  int*   deg = (int*)h2;           // alias: h2[0 .. NV)
  int*   cursor = ((int*)h2) + NV; // alias: h2[NV .. 2NV)
  __half* hh = (__half*)h2;        // alias: 6.4 MB of h2

  hipMemsetAsync(deg, 0, (size_t)NV * sizeof(int), stream);
  embed_hist_kernel<<<1024, 256, 0, stream>>>(node_feat, emb_w, emb_b, h,
                                              dst, deg);
  scan_part_kernel<<<NB, 1024, 0, stream>>>(deg, off, bsum);
  scan_fix_kernel<<<NB, 1024, 0, stream>>>(bsum, off, cursor);
  perm_kernel<<<(EV + 255) / 256, 256, 0, stream>>>(src, dst, cursor, gsrc);

  // layer 0: h -> h2 ; layer 1: h2 -> h  (ping-pong)
  aggcomb_kernel<<<3125, 256, 0, stream>>>(
      h, h2, gsrc, off, conv_w, conv_b,
      bn_gamma, bn_beta, bn_mean, bn_var);
  aggcomb_kernel<<<3125, 256, 0, stream>>>(
      h2, h, gsrc, off, conv_w + 2 * HD * HD, conv_b + HD,
      bn_gamma + HD, bn_beta + HD, bn_mean + HD, bn_var + HD);

  convert_kernel<<<NV * HD / 4 / 256, 256, 0, stream>>>(h, hh);
  score_kernel<<<((size_t)EV * 8 + 255) / 256, 256, 0, stream>>>(
      hh, src, dst, neg_dst, w_rel, out);
}

// Round 4
// 452.900 us; speedup vs baseline: 1.8606x; 1.8606x over previous
//
#include <hip/hip_runtime.h>
#include <hip/hip_fp16.h>

#define NV 50000
#define EV 800000
#define INF 128
#define HD 64
#define KNEG 5
#define NB ((NV + 1023) / 1024)   // 49 scan blocks

// ------- embed + hist fused, v2: W-in-VGPR, wave-private dbuf ---------
__global__ __launch_bounds__(256) void embed_hist_kernel(
    const float* __restrict__ feat, const float* __restrict__ W,
    const float* __restrict__ b, float* __restrict__ h,
    const int* __restrict__ dst, int* __restrict__ deg) {
  __shared__ float sF[4][2][512];   // wave x buf x (4 rows * 128) = 16 KB
  const int lane = threadIdx.x & 63;
  const int wave = threadIdx.x >> 6;
  float Wreg[INF];
#pragma unroll
  for (int k = 0; k < INF; k++) Wreg[k] = W[k * HD + lane];
  const float bias = b[lane];
  const int nwaves = gridDim.x * 4;
  const int wid = blockIdx.x * 4 + wave;   // wave-uniform
  const int ngroups = NV / 4;              // 12500 exactly

  int buf = 0;
  int g = wid;
  if (g < ngroups) {
    const float4* gp = (const float4*)(feat + (size_t)g * 512);
    const float4 a0 = gp[lane];
    const float4 a1 = gp[lane + 64];
    ((float4*)sF[wave][0])[lane] = a0;
    ((float4*)sF[wave][0])[lane + 64] = a1;
  }
  for (; g < ngroups; g += nwaves) {
    const int gn = g + nwaves;
    float4 b0, b1;
    if (gn < ngroups) {                    // wave-uniform guard
      const float4* gp = (const float4*)(feat + (size_t)gn * 512);
      b0 = gp[lane];
      b1 = gp[lane + 64];
    }
    float acc0 = bias, acc1 = bias, acc2 = bias, acc3 = bias;
    const float4* F = (const float4*)sF[wave][buf];
#pragma unroll
    for (int k4 = 0; k4 < 32; k4++) {
      const float4 x0 = F[k4];
      const float4 x1 = F[k4 + 32];
      const float4 x2 = F[k4 + 64];
      const float4 x3 = F[k4 + 96];
      const float w0 = Wreg[4 * k4 + 0];
      const float w1 = Wreg[4 * k4 + 1];
      const float w2 = Wreg[4 * k4 + 2];
      const float w3 = Wreg[4 * k4 + 3];
      acc0 = fmaf(x0.x, w0, acc0); acc0 = fmaf(x0.y, w1, acc0);
      acc0 = fmaf(x0.z, w2, acc0); acc0 = fmaf(x0.w, w3, acc0);
      acc1 = fmaf(x1.x, w0, acc1); acc1 = fmaf(x1.y, w1, acc1);
      acc1 = fmaf(x1.z, w2, acc1); acc1 = fmaf(x1.w, w3, acc1);
      acc2 = fmaf(x2.x, w0, acc2); acc2 = fmaf(x2.y, w1, acc2);
      acc2 = fmaf(x2.z, w2, acc2); acc2 = fmaf(x2.w, w3, acc2);
      acc3 = fmaf(x3.x, w0, acc3); acc3 = fmaf(x3.y, w1, acc3);
      acc3 = fmaf(x3.z, w2, acc3); acc3 = fmaf(x3.w, w3, acc3);
    }
    float* hpo = h + (size_t)g * 256 + lane;
    hpo[0] = acc0;
    hpo[64] = acc1;
    hpo[128] = acc2;
    hpo[192] = acc3;
    if (gn < ngroups) {
      ((float4*)sF[wave][buf ^ 1])[lane] = b0;
      ((float4*)sF[wave][buf ^ 1])[lane + 64] = b1;
      buf ^= 1;
    }
  }
  for (int e = blockIdx.x * 256 + threadIdx.x; e < EV; e += gridDim.x * 256)
    atomicAdd(&deg[dst[e]], 1);
}

// ------- parallel scan, pass 1 ----------------------------------------
__global__ __launch_bounds__(1024) void scan_part_kernel(
    const int* __restrict__ deg, int* __restrict__ off,
    int* __restrict__ bsum) {
  __shared__ int wsum[16];
  const int tid = threadIdx.x;
  const int lane = tid & 63;
  const int w = tid >> 6;
  const int i = blockIdx.x * 1024 + tid;
  const int v = (i < NV) ? deg[i] : 0;
  int s = v;
#pragma unroll
  for (int ofs = 1; ofs < 64; ofs <<= 1) {
    int x = __shfl_up(s, ofs, 64);
    if (lane >= ofs) s += x;
  }
  if (lane == 63) wsum[w] = s;
  __syncthreads();
  if (w == 0) {
    int t2 = (lane < 16) ? wsum[lane] : 0;
#pragma unroll
    for (int ofs = 1; ofs < 16; ofs <<= 1) {
      int x = __shfl_up(t2, ofs, 64);
      if (lane >= ofs) t2 += x;
    }
    if (lane < 16) wsum[lane] = t2;
  }
  __syncthreads();
  const int base = (w > 0) ? wsum[w - 1] : 0;
  if (i < NV) off[i] = base + s - v;
  if (tid == 0) bsum[blockIdx.x] = wsum[15];
}

// ------- parallel scan, pass 2 ----------------------------------------
__global__ __launch_bounds__(1024) void scan_fix_kernel(
    const int* __restrict__ bsum, int* __restrict__ off,
    int* __restrict__ cursor) {
  __shared__ int sbase, stot;
  const int tid = threadIdx.x;
  const int b = blockIdx.x;
  if (tid == 0) {
    int acc = 0, tot = 0;
    for (int j = 0; j < NB; j++) {
      const int x = bsum[j];
      if (j < b) acc += x;
      tot += x;
    }
    sbase = acc;
    stot = tot;
  }
  __syncthreads();
  const int i = b * 1024 + tid;
  if (i < NV) {
    const int o = off[i] + sbase;
    off[i] = o;
    cursor[i] = o;
  }
  if (b == NB - 1 && tid == 0) off[NV] = stot;
}

// ------- CSR perm -----------------------------------------------------
__global__ __launch_bounds__(256) void perm_kernel(
    const int* __restrict__ src, const int* __restrict__ dst,
    int* __restrict__ cursor, int* __restrict__ gsrc) {
  const int e = blockIdx.x * 256 + threadIdx.x;
  if (e < EV) {
    const int pos = atomicAdd(&cursor[dst[e]], 1);
    gsrc[pos] = src[e];
  }
}

// ------- fused aggregate + combine, v5 --------------------------------
// = v4 structure (one 4-node group per wave, unmasked fast path, W in
// VGPR) but NO min-waves launch-bounds hint: round-3's (256,4) forced
// VGPR 120->64, spilling the 128-float weight arrays to scratch
// (WRITE_SIZE 12.5 MB -> 475 MB). 120 VGPR already allows 4 waves/EU.
__global__ __launch_bounds__(256) void aggcomb_kernel(
    const float* __restrict__ hin, float* __restrict__ hout,
    const int* __restrict__ gsrc, const int* __restrict__ off,
    const float* __restrict__ wconv, const float* __restrict__ cb,
    const float* __restrict__ gamma, const float* __restrict__ beta,
    const float* __restrict__ mean, const float* __restrict__ var) {
  __shared__ float sS1[4][4][HD];   // wave x slot x row  (4 KB)
  __shared__ float sH[4][4][HD];    // wave x slot x own-h (4 KB)
  const int wave = threadIdx.x >> 6;
  const int lane = threadIdx.x & 63;
  const int sub = lane >> 4;   // node slot 0..3
  const int q = lane & 15;     // float4 slot within row
  const int f = lane;          // output feature in combine phase
  float Wsr[HD], Wdr[HD];
#pragma unroll
  for (int k = 0; k < HD; k++) Wsr[k] = wconv[k * HD + f];
#pragma unroll
  for (int k = 0; k < HD; k++) Wdr[k] = wconv[(HD + k) * HD + f];
  const float cbf = cb[f];
  const float gf = gamma[f];
  const float btf = beta[f];
  const float mf = mean[f];
  const float inv = rsqrtf(var[f] + 1e-3f);
  const float4* hp = (const float4*)hin;
  const int wid = blockIdx.x * 4 + wave;
  const int nw = gridDim.x * 4;
  const int ngroups = NV / 4;            // 12500 exactly
  for (int g = wid; g < ngroups; g += nw) {
    const int n0 = g * 4;
    const int n = n0 + sub;              // this slot's node
    const int j0 = off[n];
    const int deg = off[n + 1] - j0;
    int dm = deg, dmn = deg;             // wave max / min degree
    {
      int x = __shfl_xor(dm, 16, 64);
      dm = max(dm, x); dmn = min(dmn, __shfl_xor(dmn, 16, 64));
      x = __shfl_xor(dm, 32, 64);
      dm = max(dm, x); dmn = min(dmn, __shfl_xor(dmn, 32, 64));
    }
    const float4 hrow = hp[(size_t)n * 16 + q];   // own row fragment
    float4 acc = make_float4(0.f, 0.f, 0.f, 0.f);
    int base = 0;
    for (; base + 16 <= dmn; base += 16) {        // full blocks: no mask
      const int eid = gsrc[j0 + base + q];
#pragma unroll
      for (int i = 0; i < 16; i++) {
        const int a = __shfl(eid, (sub << 4) | i, 64);
        const float4 v = hp[(size_t)a * 16 + q];
        acc.x += v.x; acc.y += v.y; acc.z += v.z; acc.w += v.w;
      }
    }
    for (; base < dm; base += 16) {               // masked tail blocks
      const int e = base + q;
      const int eid = (e < deg) ? gsrc[j0 + e] : -1;
#pragma unroll
      for (int i = 0; i < 16; i++) {
        const int a = __shfl(eid, (sub << 4) | i, 64);
        const float4 v = hp[(size_t)max(a, 0) * 16 + q];
        const float msk = (a >= 0) ? 1.f : 0.f;
        acc.x = fmaf(v.x, msk, acc.x);
        acc.y = fmaf(v.y, msk, acc.y);
        acc.z = fmaf(v.z, msk, acc.z);
        acc.w = fmaf(v.w, msk, acc.w);
      }
    }
    // hand-off via wave-private LDS (in-order DS pipe; no barrier)
    ((float4*)sS1[wave][sub])[q] = acc;
    ((float4*)sH[wave][sub])[q] = hrow;
#pragma unroll
    for (int m4 = 0; m4 < 4; m4++) {
      const float4* s1p = (const float4*)sS1[wave][m4];
      const float4* hq = (const float4*)sH[wave][m4];
      float a1a = 0.f, a1b = 0.f, a2a = 0.f, a2b = 0.f;
#pragma unroll
      for (int k4 = 0; k4 < 16; k4++) {
        const float4 sv = s1p[k4];       // uniform addr -> broadcast
        const float4 hv = hq[k4];
        a1a = fmaf(sv.x, Wsr[4 * k4 + 0], a1a);
        a1b = fmaf(sv.y, Wsr[4 * k4 + 1], a1b);
        a1a = fmaf(sv.z, Wsr[4 * k4 + 2], a1a);
        a1b = fmaf(sv.w, Wsr[4 * k4 + 3], a1b);
        a2a = fmaf(hv.x, Wdr[4 * k4 + 0], a2a);
        a2b = fmaf(hv.y, Wdr[4 * k4 + 1], a2b);
        a2a = fmaf(hv.z, Wdr[4 * k4 + 2], a2a);
        a2b = fmaf(hv.w, Wdr[4 * k4 + 3], a2b);
      }
      const float a1 = a1a + a1b;
      const float a2 = a2a + a2b;
      const float hvf = sH[wave][m4][f];          // conflict-free b32
      const float d = (float)__shfl(deg, m4 << 4, 64);
      const float agg = a1 + d * a2 + d * cbf;
      const float sig = 1.f / (1.f + __expf(-agg));
      const float sp = fmaxf(hvf, 0.f) + log1pf(__expf(-fabsf(hvf)));
      float x = sig + sp;
      x = gf * (x - mf) * inv + btf;
      hout[(size_t)(n0 + m4) * HD + f] = fmaxf(x, 0.f);
    }
  }
}

// ------- convert h (fp32) -> hh (fp16, RNE) ---------------------------
__global__ __launch_bounds__(256) void convert_kernel(
    const float* __restrict__ h, __half* __restrict__ hh) {
  const int i = blockIdx.x * 256 + threadIdx.x;
  const int idx = i * 4;
  if (idx < NV * HD) {
    const float4 v = *(const float4*)(h + idx);
    __half2* o = (__half2*)(hh + idx);
    o[0] = __floats2half2_rn(v.x, v.y);
    o[1] = __floats2half2_rn(v.z, v.w);
  }
}

// ------- scores: 8 lanes/edge, fp16 rows (128 B each) -----------------
__global__ __launch_bounds__(256) void score_kernel(
    const __half* __restrict__ hh, const int* __restrict__ src,
    const int* __restrict__ dst, const int* __restrict__ neg_dst,
    const float* __restrict__ wrel, float* __restrict__ out) {
  const int tid = blockIdx.x * 256 + threadIdx.x;
  const int e = tid >> 3;
  const int q = tid & 7;
  if (e >= EV) return;
  const float4 w0 = ((const float4*)wrel)[2 * q];
  const float4 w1 = ((const float4*)wrel)[2 * q + 1];
  const int s = src[e];
  const int d = dst[e];
  int nd[KNEG];
#pragma unroll
  for (int r = 0; r < KNEG; r++) nd[r] = neg_dst[e * KNEG + r];

  const uint4* hp = (const uint4*)hh;
  const uint4 sv = hp[(size_t)s * 8 + q];
  const uint4 dv = hp[(size_t)d * 8 + q];
  uint4 nv[KNEG];
#pragma unroll
  for (int r = 0; r < KNEG; r++) nv[r] = hp[(size_t)nd[r] * 8 + q];

#define FLO(u) __half2float(__low2half(*(const __half2*)&(u)))
#define FHI(u) __half2float(__high2half(*(const __half2*)&(u)))
  const float a0 = FLO(sv.x) * w0.x, a1 = FHI(sv.x) * w0.y;
  const float a2 = FLO(sv.y) * w0.z, a3 = FHI(sv.y) * w0.w;
  const float a4 = FLO(sv.z) * w1.x, a5 = FHI(sv.z) * w1.y;
  const float a6 = FLO(sv.w) * w1.z, a7 = FHI(sv.w) * w1.w;

  float p = a0 * FLO(dv.x) + a1 * FHI(dv.x) + a2 * FLO(dv.y) + a3 * FHI(dv.y)
          + a4 * FLO(dv.z) + a5 * FHI(dv.z) + a6 * FLO(dv.w) + a7 * FHI(dv.w);
#pragma unroll
  for (int m = 4; m; m >>= 1) p += __shfl_xor(p, m, 64);
  if (q == 0) out[e] = p;

#pragma unroll
  for (int r = 0; r < KNEG; r++) {
    const uint4 v = nv[r];
    float pn = a0 * FLO(v.x) + a1 * FHI(v.x) + a2 * FLO(v.y) + a3 * FHI(v.y)
             + a4 * FLO(v.z) + a5 * FHI(v.z) + a6 * FLO(v.w) + a7 * FHI(v.w);
#pragma unroll
    for (int m = 4; m; m >>= 1) pn += __shfl_xor(pn, m, 64);
    if (q == 0) out[(size_t)EV + (size_t)e * KNEG + r] = pn;
  }
#undef FLO
#undef FHI
}

extern "C" void kernel_launch(void* const* d_in, const int* in_sizes, int n_in,
                              void* d_out, int out_size, void* d_ws, size_t ws_size,
                              hipStream_t stream) {
  const float* node_feat = (const float*)d_in[0];
  const float* emb_w     = (const float*)d_in[1];
  const float* emb_b     = (const float*)d_in[2];
  const float* conv_w    = (const float*)d_in[3];
  const float* conv_b    = (const float*)d_in[4];
  const float* bn_gamma  = (const float*)d_in[5];
  const float* bn_beta   = (const float*)d_in[6];
  const float* bn_mean   = (const float*)d_in[7];
  const float* bn_var    = (const float*)d_in[8];
  const float* w_rel     = (const float*)d_in[9];
  const int*   src       = (const int*)d_in[10];
  const int*   dst       = (const int*)d_in[11];
  const int*   neg_dst   = (const int*)d_in[12];
  float* out = (float*)d_out;

  float* h   = (float*)d_ws;
  float* h2  = h + (size_t)NV * HD;
  int*   off = (int*)(h2 + (size_t)NV * HD);
  int*   gsrc = off + (NV + 1);
  int*   bsum = gsrc + EV;
  int*   deg = (int*)h2;           // alias: h2[0 .. NV)
  int*   cursor = ((int*)h2) + NV; // alias: h2[NV .. 2NV)
  __half* hh = (__half*)h2;        // alias: 6.4 MB of h2

  hipMemsetAsync(deg, 0, (size_t)NV * sizeof(int), stream);
  embed_hist_kernel<<<1024, 256, 0, stream>>>(node_feat, emb_w, emb_b, h,
                                              dst, deg);
  scan_part_kernel<<<NB, 1024, 0, stream>>>(deg, off, bsum);
  scan_fix_kernel<<<NB, 1024, 0, stream>>>(bsum, off, cursor);
  perm_kernel<<<(EV + 255) / 256, 256, 0, stream>>>(src, dst, cursor, gsrc);

  // layer 0: h -> h2 ; layer 1: h2 -> h  (ping-pong)
  aggcomb_kernel<<<3125, 256, 0, stream>>>(
      h, h2, gsrc, off, conv_w, conv_b,
      bn_gamma, bn_beta, bn_mean, bn_var);
  aggcomb_kernel<<<3125, 256, 0, stream>>>(
      h2, h, gsrc, off, conv_w + 2 * HD * HD, conv_b + HD,
      bn_gamma + HD, bn_beta + HD, bn_mean + HD, bn_var + HD);

  convert_kernel<<<NV * HD / 4 / 256, 256, 0, stream>>>(h, hh);
  score_kernel<<<((size_t)EV * 8 + 255) / 256, 256, 0, stream>>>(
      hh, src, dst, neg_dst, w_rel, out);
}

// Round 5
// 358.765 us; speedup vs baseline: 2.3488x; 1.2624x over previous
//
#include <hip/hip_runtime.h>
#include <hip/hip_fp16.h>

#define NV 50000
#define EV 800000
#define INF 128
#define HD 64
#define KNEG 5
#define NB ((NV + 1023) / 1024)   // 49 scan blocks

// ------- embed + hist fused, v2: W-in-VGPR, wave-private dbuf ---------
__global__ __launch_bounds__(256) void embed_hist_kernel(
    const float* __restrict__ feat, const float* __restrict__ W,
    const float* __restrict__ b, float* __restrict__ h,
    const int* __restrict__ dst, int* __restrict__ deg) {
  __shared__ float sF[4][2][512];   // wave x buf x (4 rows * 128) = 16 KB
  const int lane = threadIdx.x & 63;
  const int wave = threadIdx.x >> 6;
  float Wreg[INF];
#pragma unroll
  for (int k = 0; k < INF; k++) Wreg[k] = W[k * HD + lane];
  const float bias = b[lane];
  const int nwaves = gridDim.x * 4;
  const int wid = blockIdx.x * 4 + wave;   // wave-uniform
  const int ngroups = NV / 4;              // 12500 exactly

  int buf = 0;
  int g = wid;
  if (g < ngroups) {
    const float4* gp = (const float4*)(feat + (size_t)g * 512);
    const float4 a0 = gp[lane];
    const float4 a1 = gp[lane + 64];
    ((float4*)sF[wave][0])[lane] = a0;
    ((float4*)sF[wave][0])[lane + 64] = a1;
  }
  for (; g < ngroups; g += nwaves) {
    const int gn = g + nwaves;
    float4 b0, b1;
    if (gn < ngroups) {                    // wave-uniform guard
      const float4* gp = (const float4*)(feat + (size_t)gn * 512);
      b0 = gp[lane];
      b1 = gp[lane + 64];
    }
    float acc0 = bias, acc1 = bias, acc2 = bias, acc3 = bias;
    const float4* F = (const float4*)sF[wave][buf];
#pragma unroll
    for (int k4 = 0; k4 < 32; k4++) {
      const float4 x0 = F[k4];
      const float4 x1 = F[k4 + 32];
      const float4 x2 = F[k4 + 64];
      const float4 x3 = F[k4 + 96];
      const float w0 = Wreg[4 * k4 + 0];
      const float w1 = Wreg[4 * k4 + 1];
      const float w2 = Wreg[4 * k4 + 2];
      const float w3 = Wreg[4 * k4 + 3];
      acc0 = fmaf(x0.x, w0, acc0); acc0 = fmaf(x0.y, w1, acc0);
      acc0 = fmaf(x0.z, w2, acc0); acc0 = fmaf(x0.w, w3, acc0);
      acc1 = fmaf(x1.x, w0, acc1); acc1 = fmaf(x1.y, w1, acc1);
      acc1 = fmaf(x1.z, w2, acc1); acc1 = fmaf(x1.w, w3, acc1);
      acc2 = fmaf(x2.x, w0, acc2); acc2 = fmaf(x2.y, w1, acc2);
      acc2 = fmaf(x2.z, w2, acc2); acc2 = fmaf(x2.w, w3, acc2);
      acc3 = fmaf(x3.x, w0, acc3); acc3 = fmaf(x3.y, w1, acc3);
      acc3 = fmaf(x3.z, w2, acc3); acc3 = fmaf(x3.w, w3, acc3);
    }
    float* hpo = h + (size_t)g * 256 + lane;
    hpo[0] = acc0;
    hpo[64] = acc1;
    hpo[128] = acc2;
    hpo[192] = acc3;
    if (gn < ngroups) {
      ((float4*)sF[wave][buf ^ 1])[lane] = b0;
      ((float4*)sF[wave][buf ^ 1])[lane + 64] = b1;
      buf ^= 1;
    }
  }
  for (int e = blockIdx.x * 256 + threadIdx.x; e < EV; e += gridDim.x * 256)
    atomicAdd(&deg[dst[e]], 1);
}

// ------- parallel scan, pass 1 ----------------------------------------
__global__ __launch_bounds__(1024) void scan_part_kernel(
    const int* __restrict__ deg, int* __restrict__ off,
    int* __restrict__ bsum) {
  __shared__ int wsum[16];
  const int tid = threadIdx.x;
  const int lane = tid & 63;
  const int w = tid >> 6;
  const int i = blockIdx.x * 1024 + tid;
  const int v = (i < NV) ? deg[i] : 0;
  int s = v;
#pragma unroll
  for (int ofs = 1; ofs < 64; ofs <<= 1) {
    int x = __shfl_up(s, ofs, 64);
    if (lane >= ofs) s += x;
  }
  if (lane == 63) wsum[w] = s;
  __syncthreads();
  if (w == 0) {
    int t2 = (lane < 16) ? wsum[lane] : 0;
#pragma unroll
    for (int ofs = 1; ofs < 16; ofs <<= 1) {
      int x = __shfl_up(t2, ofs, 64);
      if (lane >= ofs) t2 += x;
    }
    if (lane < 16) wsum[lane] = t2;
  }
  __syncthreads();
  const int base = (w > 0) ? wsum[w - 1] : 0;
  if (i < NV) off[i] = base + s - v;
  if (tid == 0) bsum[blockIdx.x] = wsum[15];
}

// ------- parallel scan, pass 2 ----------------------------------------
__global__ __launch_bounds__(1024) void scan_fix_kernel(
    const int* __restrict__ bsum, int* __restrict__ off,
    int* __restrict__ cursor) {
  __shared__ int sbase, stot;
  const int tid = threadIdx.x;
  const int b = blockIdx.x;
  if (tid == 0) {
    int acc = 0, tot = 0;
    for (int j = 0; j < NB; j++) {
      const int x = bsum[j];
      if (j < b) acc += x;
      tot += x;
    }
    sbase = acc;
    stot = tot;
  }
  __syncthreads();
  const int i = b * 1024 + tid;
  if (i < NV) {
    const int o = off[i] + sbase;
    off[i] = o;
    cursor[i] = o;
  }
  if (b == NB - 1 && tid == 0) off[NV] = stot;
}

// ------- CSR perm -----------------------------------------------------
__global__ __launch_bounds__(256) void perm_kernel(
    const int* __restrict__ src, const int* __restrict__ dst,
    int* __restrict__ cursor, int* __restrict__ gsrc) {
  const int e = blockIdx.x * 256 + threadIdx.x;
  if (e < EV) {
    const int pos = atomicAdd(&cursor[dst[e]], 1);
    gsrc[pos] = src[e];
  }
}

// ------- fused aggregate + combine, v6 = r2-verified body, grid 1024 --
// r2 measured: VGPR 120 (4 waves/EU cap OK), 56.6 us at grid 512
// (8 waves/CU resident). Only diagnosed defect: grid-limited residency.
// This round: identical body, grid 512 -> 1024 (16 waves/CU = the VGPR
// cap; ~3 groups/wave keeps weight-preload amortization). r3/r4 taught:
// (256,4) hint spills the weight regs; one-group-per-wave (grid 3125)
// kills amortization and its extra path pushed VGPR past 128.
__global__ __launch_bounds__(256) void aggcomb_kernel(
    const float* __restrict__ hin, float* __restrict__ hout,
    const int* __restrict__ gsrc, const int* __restrict__ off,
    const float* __restrict__ wconv, const float* __restrict__ cb,
    const float* __restrict__ gamma, const float* __restrict__ beta,
    const float* __restrict__ mean, const float* __restrict__ var) {
  __shared__ float sS1[4][4][HD];   // wave x slot x row  (4 KB)
  __shared__ float sH[4][4][HD];    // wave x slot x own-h (4 KB)
  const int wave = threadIdx.x >> 6;
  const int lane = threadIdx.x & 63;
  const int sub = lane >> 4;   // node slot 0..3
  const int q = lane & 15;     // float4 slot within row
  const int f = lane;          // output feature in combine phase
  float Wsr[HD], Wdr[HD];
#pragma unroll
  for (int k = 0; k < HD; k++) Wsr[k] = wconv[k * HD + f];
#pragma unroll
  for (int k = 0; k < HD; k++) Wdr[k] = wconv[(HD + k) * HD + f];
  const float cbf = cb[f];
  const float gf = gamma[f];
  const float btf = beta[f];
  const float mf = mean[f];
  const float inv = rsqrtf(var[f] + 1e-3f);
  const float4* hp = (const float4*)hin;
  const int wid = blockIdx.x * 4 + wave;
  const int nw = gridDim.x * 4;
  const int ngroups = NV / 4;            // 12500 exactly
  for (int g = wid; g < ngroups; g += nw) {
    const int n0 = g * 4;
    const int n = n0 + sub;              // this slot's node
    const int j0 = off[n];
    const int deg = off[n + 1] - j0;
    int dm = deg;                        // wave-max degree
    dm = max(dm, __shfl_xor(dm, 16, 64));
    dm = max(dm, __shfl_xor(dm, 32, 64));
    const float4 hrow = hp[(size_t)n * 16 + q];   // own row fragment
    float4 acc = make_float4(0.f, 0.f, 0.f, 0.f);
    for (int base = 0; base < dm; base += 16) {
      const int e = base + q;
      const int eid = (e < deg) ? gsrc[j0 + e] : -1;
#pragma unroll
      for (int i = 0; i < 16; i++) {
        const int a = __shfl(eid, (sub << 4) | i, 64);
        const float4 v = hp[(size_t)max(a, 0) * 16 + q];
        const float msk = (a >= 0) ? 1.f : 0.f;
        acc.x = fmaf(v.x, msk, acc.x);
        acc.y = fmaf(v.y, msk, acc.y);
        acc.z = fmaf(v.z, msk, acc.z);
        acc.w = fmaf(v.w, msk, acc.w);
      }
    }
    // hand-off via wave-private LDS (in-order DS pipe; no barrier)
    ((float4*)sS1[wave][sub])[q] = acc;
    ((float4*)sH[wave][sub])[q] = hrow;
#pragma unroll
    for (int m4 = 0; m4 < 4; m4++) {
      const float4* s1p = (const float4*)sS1[wave][m4];
      const float4* hq = (const float4*)sH[wave][m4];
      float a1a = 0.f, a1b = 0.f, a2a = 0.f, a2b = 0.f;
#pragma unroll
      for (int k4 = 0; k4 < 16; k4++) {
        const float4 sv = s1p[k4];       // uniform addr -> broadcast
        const float4 hv = hq[k4];
        a1a = fmaf(sv.x, Wsr[4 * k4 + 0], a1a);
        a1b = fmaf(sv.y, Wsr[4 * k4 + 1], a1b);
        a1a = fmaf(sv.z, Wsr[4 * k4 + 2], a1a);
        a1b = fmaf(sv.w, Wsr[4 * k4 + 3], a1b);
        a2a = fmaf(hv.x, Wdr[4 * k4 + 0], a2a);
        a2b = fmaf(hv.y, Wdr[4 * k4 + 1], a2b);
        a2a = fmaf(hv.z, Wdr[4 * k4 + 2], a2a);
        a2b = fmaf(hv.w, Wdr[4 * k4 + 3], a2b);
      }
      const float a1 = a1a + a1b;
      const float a2 = a2a + a2b;
      const float hvf = sH[wave][m4][f];          // conflict-free b32
      const float d = (float)__shfl(deg, m4 << 4, 64);
      const float agg = a1 + d * a2 + d * cbf;
      const float sig = 1.f / (1.f + __expf(-agg));
      const float sp = fmaxf(hvf, 0.f) + log1pf(__expf(-fabsf(hvf)));
      float x = sig + sp;
      x = gf * (x - mf) * inv + btf;
      hout[(size_t)(n0 + m4) * HD + f] = fmaxf(x, 0.f);
    }
  }
}

// ------- convert h (fp32) -> hh (fp16, RNE) ---------------------------
__global__ __launch_bounds__(256) void convert_kernel(
    const float* __restrict__ h, __half* __restrict__ hh) {
  const int i = blockIdx.x * 256 + threadIdx.x;
  const int idx = i * 4;
  if (idx < NV * HD) {
    const float4 v = *(const float4*)(h + idx);
    __half2* o = (__half2*)(hh + idx);
    o[0] = __floats2half2_rn(v.x, v.y);
    o[1] = __floats2half2_rn(v.z, v.w);
  }
}

// ------- scores: 8 lanes/edge, fp16 rows (128 B each) -----------------
__global__ __launch_bounds__(256) void score_kernel(
    const __half* __restrict__ hh, const int* __restrict__ src,
    const int* __restrict__ dst, const int* __restrict__ neg_dst,
    const float* __restrict__ wrel, float* __restrict__ out) {
  const int tid = blockIdx.x * 256 + threadIdx.x;
  const int e = tid >> 3;
  const int q = tid & 7;
  if (e >= EV) return;
  const float4 w0 = ((const float4*)wrel)[2 * q];
  const float4 w1 = ((const float4*)wrel)[2 * q + 1];
  const int s = src[e];
  const int d = dst[e];
  int nd[KNEG];
#pragma unroll
  for (int r = 0; r < KNEG; r++) nd[r] = neg_dst[e * KNEG + r];

  const uint4* hp = (const uint4*)hh;
  const uint4 sv = hp[(size_t)s * 8 + q];
  const uint4 dv = hp[(size_t)d * 8 + q];
  uint4 nv[KNEG];
#pragma unroll
  for (int r = 0; r < KNEG; r++) nv[r] = hp[(size_t)nd[r] * 8 + q];

#define FLO(u) __half2float(__low2half(*(const __half2*)&(u)))
#define FHI(u) __half2float(__high2half(*(const __half2*)&(u)))
  const float a0 = FLO(sv.x) * w0.x, a1 = FHI(sv.x) * w0.y;
  const float a2 = FLO(sv.y) * w0.z, a3 = FHI(sv.y) * w0.w;
  const float a4 = FLO(sv.z) * w1.x, a5 = FHI(sv.z) * w1.y;
  const float a6 = FLO(sv.w) * w1.z, a7 = FHI(sv.w) * w1.w;

  float p = a0 * FLO(dv.x) + a1 * FHI(dv.x) + a2 * FLO(dv.y) + a3 * FHI(dv.y)
          + a4 * FLO(dv.z) + a5 * FHI(dv.z) + a6 * FLO(dv.w) + a7 * FHI(dv.w);
#pragma unroll
  for (int m = 4; m; m >>= 1) p += __shfl_xor(p, m, 64);
  if (q == 0) out[e] = p;

#pragma unroll
  for (int r = 0; r < KNEG; r++) {
    const uint4 v = nv[r];
    float pn = a0 * FLO(v.x) + a1 * FHI(v.x) + a2 * FLO(v.y) + a3 * FHI(v.y)
             + a4 * FLO(v.z) + a5 * FHI(v.z) + a6 * FLO(v.w) + a7 * FHI(v.w);
#pragma unroll
    for (int m = 4; m; m >>= 1) pn += __shfl_xor(pn, m, 64);
    if (q == 0) out[(size_t)EV + (size_t)e * KNEG + r] = pn;
  }
#undef FLO
#undef FHI
}

extern "C" void kernel_launch(void* const* d_in, const int* in_sizes, int n_in,
                              void* d_out, int out_size, void* d_ws, size_t ws_size,
                              hipStream_t stream) {
  const float* node_feat = (const float*)d_in[0];
  const float* emb_w     = (const float*)d_in[1];
  const float* emb_b     = (const float*)d_in[2];
  const float* conv_w    = (const float*)d_in[3];
  const float* conv_b    = (const float*)d_in[4];
  const float* bn_gamma  = (const float*)d_in[5];
  const float* bn_beta   = (const float*)d_in[6];
  const float* bn_mean   = (const float*)d_in[7];
  const float* bn_var    = (const float*)d_in[8];
  const float* w_rel     = (const float*)d_in[9];
  const int*   src       = (const int*)d_in[10];
  const int*   dst       = (const int*)d_in[11];
  const int*   neg_dst   = (const int*)d_in[12];
  float* out = (float*)d_out;

  float* h   = (float*)d_ws;
  float* h2  = h + (size_t)NV * HD;
  int*   off = (int*)(h2 + (size_t)NV * HD);
  int*   gsrc = off + (NV + 1);
  int*   bsum = gsrc + EV;
  int*   deg = (int*)h2;           // alias: h2[0 .. NV)
  int*   cursor = ((int*)h2) + NV; // alias: h2[NV .. 2NV)
  __half* hh = (__half*)h2;        // alias: 6.4 MB of h2

  hipMemsetAsync(deg, 0, (size_t)NV * sizeof(int), stream);
  embed_hist_kernel<<<1024, 256, 0, stream>>>(node_feat, emb_w, emb_b, h,
                                              dst, deg);
  scan_part_kernel<<<NB, 1024, 0, stream>>>(deg, off, bsum);
  scan_fix_kernel<<<NB, 1024, 0, stream>>>(bsum, off, cursor);
  perm_kernel<<<(EV + 255) / 256, 256, 0, stream>>>(src, dst, cursor, gsrc);

  // layer 0: h -> h2 ; layer 1: h2 -> h  (ping-pong)
  aggcomb_kernel<<<1024, 256, 0, stream>>>(
      h, h2, gsrc, off, conv_w, conv_b,
      bn_gamma, bn_beta, bn_mean, bn_var);
  aggcomb_kernel<<<1024, 256, 0, stream>>>(
      h2, h, gsrc, off, conv_w + 2 * HD * HD, conv_b + HD,
      bn_gamma + HD, bn_beta + HD, bn_mean + HD, bn_var + HD);

  convert_kernel<<<NV * HD / 4 / 256, 256, 0, stream>>>(h, hh);
  score_kernel<<<((size_t)EV * 8 + 255) / 256, 256, 0, stream>>>(
      hh, src, dst, neg_dst, w_rel, out);
}

// Round 7
// 330.019 us; speedup vs baseline: 2.5534x; 1.0871x over previous
//
#include <hip/hip_runtime.h>
#include <hip/hip_fp16.h>

#define NV 50000
#define EV 800000
#define INF 128
#define HD 64
#define KNEG 5
#define NB ((NV + 1023) / 1024)   // 49 scan blocks

// ------- embed + hist fused, v3: W-in-VGPR, fp16 h output -------------
// h = feat @ W + b, stored fp16 (RNE). fp16 h (6.4 MB) nearly fits a
// 4 MB per-XCD L2 -> the downstream random-row gather flips from ~33%
// HBM-miss to mostly-L2-hit, and bytes/row halve (128 B).
__global__ __launch_bounds__(256) void embed_hist_kernel(
    const float* __restrict__ feat, const float* __restrict__ W,
    const float* __restrict__ b, __half* __restrict__ h,
    const int* __restrict__ dst, int* __restrict__ deg) {
  __shared__ float sF[4][2][512];   // wave x buf x (4 rows * 128) = 16 KB
  const int lane = threadIdx.x & 63;
  const int wave = threadIdx.x >> 6;
  float Wreg[INF];
#pragma unroll
  for (int k = 0; k < INF; k++) Wreg[k] = W[k * HD + lane];
  const float bias = b[lane];
  const int nwaves = gridDim.x * 4;
  const int wid = blockIdx.x * 4 + wave;   // wave-uniform
  const int ngroups = NV / 4;              // 12500 exactly

  int buf = 0;
  int g = wid;
  if (g < ngroups) {
    const float4* gp = (const float4*)(feat + (size_t)g * 512);
    const float4 a0 = gp[lane];
    const float4 a1 = gp[lane + 64];
    ((float4*)sF[wave][0])[lane] = a0;
    ((float4*)sF[wave][0])[lane + 64] = a1;
  }
  for (; g < ngroups; g += nwaves) {
    const int gn = g + nwaves;
    float4 b0, b1;
    if (gn < ngroups) {                    // wave-uniform guard
      const float4* gp = (const float4*)(feat + (size_t)gn * 512);
      b0 = gp[lane];
      b1 = gp[lane + 64];
    }
    float acc0 = bias, acc1 = bias, acc2 = bias, acc3 = bias;
    const float4* F = (const float4*)sF[wave][buf];
#pragma unroll
    for (int k4 = 0; k4 < 32; k4++) {
      const float4 x0 = F[k4];
      const float4 x1 = F[k4 + 32];
      const float4 x2 = F[k4 + 64];
      const float4 x3 = F[k4 + 96];
      const float w0 = Wreg[4 * k4 + 0];
      const float w1 = Wreg[4 * k4 + 1];
      const float w2 = Wreg[4 * k4 + 2];
      const float w3 = Wreg[4 * k4 + 3];
      acc0 = fmaf(x0.x, w0, acc0); acc0 = fmaf(x0.y, w1, acc0);
      acc0 = fmaf(x0.z, w2, acc0); acc0 = fmaf(x0.w, w3, acc0);
      acc1 = fmaf(x1.x, w0, acc1); acc1 = fmaf(x1.y, w1, acc1);
      acc1 = fmaf(x1.z, w2, acc1); acc1 = fmaf(x1.w, w3, acc1);
      acc2 = fmaf(x2.x, w0, acc2); acc2 = fmaf(x2.y, w1, acc2);
      acc2 = fmaf(x2.z, w2, acc2); acc2 = fmaf(x2.w, w3, acc2);
      acc3 = fmaf(x3.x, w0, acc3); acc3 = fmaf(x3.y, w1, acc3);
      acc3 = fmaf(x3.z, w2, acc3); acc3 = fmaf(x3.w, w3, acc3);
    }
    __half* hpo = h + (size_t)g * 256 + lane;   // 4 coalesced 128B stores
    hpo[0]   = __float2half_rn(acc0);
    hpo[64]  = __float2half_rn(acc1);
    hpo[128] = __float2half_rn(acc2);
    hpo[192] = __float2half_rn(acc3);
    if (gn < ngroups) {
      ((float4*)sF[wave][buf ^ 1])[lane] = b0;
      ((float4*)sF[wave][buf ^ 1])[lane + 64] = b1;
      buf ^= 1;
    }
  }
  for (int e = blockIdx.x * 256 + threadIdx.x; e < EV; e += gridDim.x * 256)
    atomicAdd(&deg[dst[e]], 1);
}

// ------- parallel scan, pass 1 ----------------------------------------
__global__ __launch_bounds__(1024) void scan_part_kernel(
    const int* __restrict__ deg, int* __restrict__ off,
    int* __restrict__ bsum) {
  __shared__ int wsum[16];
  const int tid = threadIdx.x;
  const int lane = tid & 63;
  const int w = tid >> 6;
  const int i = blockIdx.x * 1024 + tid;
  const int v = (i < NV) ? deg[i] : 0;
  int s = v;
#pragma unroll
  for (int ofs = 1; ofs < 64; ofs <<= 1) {
    int x = __shfl_up(s, ofs, 64);
    if (lane >= ofs) s += x;
  }
  if (lane == 63) wsum[w] = s;
  __syncthreads();
  if (w == 0) {
    int t2 = (lane < 16) ? wsum[lane] : 0;
#pragma unroll
    for (int ofs = 1; ofs < 16; ofs <<= 1) {
      int x = __shfl_up(t2, ofs, 64);
      if (lane >= ofs) t2 += x;
    }
    if (lane < 16) wsum[lane] = t2;
  }
  __syncthreads();
  const int base = (w > 0) ? wsum[w - 1] : 0;
  if (i < NV) off[i] = base + s - v;
  if (tid == 0) bsum[blockIdx.x] = wsum[15];
}

// ------- parallel scan, pass 2 ----------------------------------------
__global__ __launch_bounds__(1024) void scan_fix_kernel(
    const int* __restrict__ bsum, int* __restrict__ off,
    int* __restrict__ cursor) {
  __shared__ int sbase, stot;
  const int tid = threadIdx.x;
  const int b = blockIdx.x;
  if (tid == 0) {
    int acc = 0, tot = 0;
    for (int j = 0; j < NB; j++) {
      const int x = bsum[j];
      if (j < b) acc += x;
      tot += x;
    }
    sbase = acc;
    stot = tot;
  }
  __syncthreads();
  const int i = b * 1024 + tid;
  if (i < NV) {
    const int o = off[i] + sbase;
    off[i] = o;
    cursor[i] = o;
  }
  if (b == NB - 1 && tid == 0) off[NV] = stot;
}

// ------- CSR perm -----------------------------------------------------
__global__ __launch_bounds__(256) void perm_kernel(
    const int* __restrict__ src, const int* __restrict__ dst,
    int* __restrict__ cursor, int* __restrict__ gsrc) {
  const int e = blockIdx.x * 256 + threadIdx.x;
  if (e < EV) {
    const int pos = atomicAdd(&cursor[dst[e]], 1);
    gsrc[pos] = src[e];
  }
}

// ------- fused aggregate + combine, v7: fp16 rows, r2-proven schedule -
// r2 body (grid 512, VGPR 120, measured best 56.6 us) with the gather
// and own-row reads switched to fp16 (uint2 = 4 halves per lane;
// accumulate fp32). Combine (s1|h)@W stays fp32 in LDS. Output fp16.
__global__ __launch_bounds__(256) void aggcomb_kernel(
    const __half* __restrict__ hin, __half* __restrict__ hout,
    const int* __restrict__ gsrc, const int* __restrict__ off,
    const float* __restrict__ wconv, const float* __restrict__ cb,
    const float* __restrict__ gamma, const float* __restrict__ beta,
    const float* __restrict__ mean, const float* __restrict__ var) {
  __shared__ float sS1[4][4][HD];   // wave x slot x row  (4 KB)
  __shared__ float sH[4][4][HD];    // wave x slot x own-h (4 KB)
  const int wave = threadIdx.x >> 6;
  const int lane = threadIdx.x & 63;
  const int sub = lane >> 4;   // node slot 0..3
  const int q = lane & 15;     // uint2 slot within fp16 row
  const int f = lane;          // output feature in combine phase
  float Wsr[HD], Wdr[HD];
#pragma unroll
  for (int k = 0; k < HD; k++) Wsr[k] = wconv[k * HD + f];
#pragma unroll
  for (int k = 0; k < HD; k++) Wdr[k] = wconv[(HD + k) * HD + f];
  const float cbf = cb[f];
  const float gf = gamma[f];
  const float btf = beta[f];
  const float mf = mean[f];
  const float inv = rsqrtf(var[f] + 1e-3f);
  const uint2* hp = (const uint2*)hin;   // 4 halves/lane, 16 lanes/row
  const int wid = blockIdx.x * 4 + wave;
  const int nw = gridDim.x * 4;
  const int ngroups = NV / 4;            // 12500 exactly
  for (int g = wid; g < ngroups; g += nw) {
    const int n0 = g * 4;
    const int n = n0 + sub;              // this slot's node
    const int j0 = off[n];
    const int deg = off[n + 1] - j0;
    int dm = deg;                        // wave-max degree
    dm = max(dm, __shfl_xor(dm, 16, 64));
    dm = max(dm, __shfl_xor(dm, 32, 64));
    const uint2 hrv = hp[(size_t)n * 16 + q];     // own row fragment
    float4 acc = make_float4(0.f, 0.f, 0.f, 0.f);
    for (int base = 0; base < dm; base += 16) {
      const int e = base + q;
      const int eid = (e < deg) ? gsrc[j0 + e] : -1;
#pragma unroll
      for (int i = 0; i < 16; i++) {
        const int a = __shfl(eid, (sub << 4) | i, 64);
        const uint2 v = hp[(size_t)max(a, 0) * 16 + q];
        const __half2 p0 = *(const __half2*)&v.x;
        const __half2 p1 = *(const __half2*)&v.y;
        const float msk = (a >= 0) ? 1.f : 0.f;
        acc.x = fmaf(__low2float(p0),  msk, acc.x);
        acc.y = fmaf(__high2float(p0), msk, acc.y);
        acc.z = fmaf(__low2float(p1),  msk, acc.z);
        acc.w = fmaf(__high2float(p1), msk, acc.w);
      }
    }
    // hand-off via wave-private LDS (in-order DS pipe; no barrier)
    {
      const __half2 p0 = *(const __half2*)&hrv.x;
      const __half2 p1 = *(const __half2*)&hrv.y;
      const float4 hrowf = make_float4(__low2float(p0), __high2float(p0),
                                       __low2float(p1), __high2float(p1));
      ((float4*)sS1[wave][sub])[q] = acc;
      ((float4*)sH[wave][sub])[q] = hrowf;
    }
#pragma unroll
    for (int m4 = 0; m4 < 4; m4++) {
      const float4* s1p = (const float4*)sS1[wave][m4];
      const float4* hq = (const float4*)sH[wave][m4];
      float a1a = 0.f, a1b = 0.f, a2a = 0.f, a2b = 0.f;
#pragma unroll
      for (int k4 = 0; k4 < 16; k4++) {
        const float4 sv = s1p[k4];       // uniform addr -> broadcast
        const float4 hv = hq[k4];
        a1a = fmaf(sv.x, Wsr[4 * k4 + 0], a1a);
        a1b = fmaf(sv.y, Wsr[4 * k4 + 1], a1b);
        a1a = fmaf(sv.z, Wsr[4 * k4 + 2], a1a);
        a1b = fmaf(sv.w, Wsr[4 * k4 + 3], a1b);
        a2a = fmaf(hv.x, Wdr[4 * k4 + 0], a2a);
        a2b = fmaf(hv.y, Wdr[4 * k4 + 1], a2b);
        a2a = fmaf(hv.z, Wdr[4 * k4 + 2], a2a);
        a2b = fmaf(hv.w, Wdr[4 * k4 + 3], a2b);
      }
      const float a1 = a1a + a1b;
      const float a2 = a2a + a2b;
      const float hvf = sH[wave][m4][f];          // conflict-free b32
      const float d = (float)__shfl(deg, m4 << 4, 64);
      const float agg = a1 + d * a2 + d * cbf;
      const float sig = 1.f / (1.f + __expf(-agg));
      const float sp = fmaxf(hvf, 0.f) + log1pf(__expf(-fabsf(hvf)));
      float x = sig + sp;
      x = gf * (x - mf) * inv + btf;
      hout[(size_t)(n0 + m4) * HD + f] = __float2half_rn(fmaxf(x, 0.f));
    }
  }
}

// ------- scores: 8 lanes/edge, fp16 rows (128 B each) -----------------
__global__ __launch_bounds__(256) void score_kernel(
    const __half* __restrict__ hh, const int* __restrict__ src,
    const int* __restrict__ dst, const int* __restrict__ neg_dst,
    const float* __restrict__ wrel, float* __restrict__ out) {
  const int tid = blockIdx.x * 256 + threadIdx.x;
  const int e = tid >> 3;
  const int q = tid & 7;
  if (e >= EV) return;
  const float4 w0 = ((const float4*)wrel)[2 * q];
  const float4 w1 = ((const float4*)wrel)[2 * q + 1];
  const int s = src[e];
  const int d = dst[e];
  int nd[KNEG];
#pragma unroll
  for (int r = 0; r < KNEG; r++) nd[r] = neg_dst[e * KNEG + r];

  const uint4* hp = (const uint4*)hh;
  const uint4 sv = hp[(size_t)s * 8 + q];
  const uint4 dv = hp[(size_t)d * 8 + q];
  uint4 nv[KNEG];
#pragma unroll
  for (int r = 0; r < KNEG; r++) nv[r] = hp[(size_t)nd[r] * 8 + q];

#define FLO(u) __half2float(__low2half(*(const __half2*)&(u)))
#define FHI(u) __half2float(__high2half(*(const __half2*)&(u)))
  const float a0 = FLO(sv.x) * w0.x, a1 = FHI(sv.x) * w0.y;
  const float a2 = FLO(sv.y) * w0.z, a3 = FHI(sv.y) * w0.w;
  const float a4 = FLO(sv.z) * w1.x, a5 = FHI(sv.z) * w1.y;
  const float a6 = FLO(sv.w) * w1.z, a7 = FHI(sv.w) * w1.w;

  float p = a0 * FLO(dv.x) + a1 * FHI(dv.x) + a2 * FLO(dv.y) + a3 * FHI(dv.y)
          + a4 * FLO(dv.z) + a5 * FHI(dv.z) + a6 * FLO(dv.w) + a7 * FHI(dv.w);
#pragma unroll
  for (int m = 4; m; m >>= 1) p += __shfl_xor(p, m, 64);
  if (q == 0) out[e] = p;

#pragma unroll
  for (int r = 0; r < KNEG; r++) {
    const uint4 v = nv[r];
    float pn = a0 * FLO(v.x) + a1 * FHI(v.x) + a2 * FLO(v.y) + a3 * FHI(v.y)
             + a4 * FLO(v.z) + a5 * FHI(v.z) + a6 * FLO(v.w) + a7 * FHI(v.w);
#pragma unroll
    for (int m = 4; m; m >>= 1) pn += __shfl_xor(pn, m, 64);
    if (q == 0) out[(size_t)EV + (size_t)e * KNEG + r] = pn;
  }
#undef FLO
#undef FHI
}

extern "C" void kernel_launch(void* const* d_in, const int* in_sizes, int n_in,
                              void* d_out, int out_size, void* d_ws, size_t ws_size,
                              hipStream_t stream) {
  const float* node_feat = (const float*)d_in[0];
  const float* emb_w     = (const float*)d_in[1];
  const float* emb_b     = (const float*)d_in[2];
  const float* conv_w    = (const float*)d_in[3];
  const float* conv_b    = (const float*)d_in[4];
  const float* bn_gamma  = (const float*)d_in[5];
  const float* bn_beta   = (const float*)d_in[6];
  const float* bn_mean   = (const float*)d_in[7];
  const float* bn_var    = (const float*)d_in[8];
  const float* w_rel     = (const float*)d_in[9];
  const int*   src       = (const int*)d_in[10];
  const int*   dst       = (const int*)d_in[11];
  const int*   neg_dst   = (const int*)d_in[12];
  float* out = (float*)d_out;

  // ws layout (fp16 ping-pong): H0 | H1 | off (N+1) | gsrc (E) | bsum
  // deg/cursor alias H1 (H1 first written by layer-0 aggcomb, after
  // deg/cursor are dead). Total ~17 MB.
  __half* H0 = (__half*)d_ws;                    // NV x HD fp16
  __half* H1 = H0 + (size_t)NV * HD;
  int*   off  = (int*)(H1 + (size_t)NV * HD);
  int*   gsrc = off + (NV + 1);
  int*   bsum = gsrc + EV;
  int*   deg    = (int*)H1;            // alias: H1[0 .. NV)
  int*   cursor = ((int*)H1) + NV;     // alias: H1[NV .. 2NV)

  hipMemsetAsync(deg, 0, (size_t)NV * sizeof(int), stream);
  embed_hist_kernel<<<1024, 256, 0, stream>>>(node_feat, emb_w, emb_b, H0,
                                              dst, deg);
  scan_part_kernel<<<NB, 1024, 0, stream>>>(deg, off, bsum);
  scan_fix_kernel<<<NB, 1024, 0, stream>>>(bsum, off, cursor);
  perm_kernel<<<(EV + 255) / 256, 256, 0, stream>>>(src, dst, cursor, gsrc);

  // layer 0: H0 -> H1 ; layer 1: H1 -> H0  (ping-pong)
  aggcomb_kernel<<<512, 256, 0, stream>>>(
      H0, H1, gsrc, off, conv_w, conv_b,
      bn_gamma, bn_beta, bn_mean, bn_var);
  aggcomb_kernel<<<512, 256, 0, stream>>>(
      H1, H0, gsrc, off, conv_w + 2 * HD * HD, conv_b + HD,
      bn_gamma + HD, bn_beta + HD, bn_mean + HD, bn_var + HD);

  score_kernel<<<((size_t)EV * 8 + 255) / 256, 256, 0, stream>>>(
      H0, src, dst, neg_dst, w_rel, out);
}

// Round 8
// 327.459 us; speedup vs baseline: 2.5734x; 1.0078x over previous
//
#include <hip/hip_runtime.h>
#include <hip/hip_fp16.h>

#define NV 50000
#define EV 800000
#define INF 128
#define HD 64
#define KNEG 5
#define NB ((NV + 1023) / 1024)   // 49 scan blocks

#if defined(__has_builtin)
#if __has_builtin(__builtin_amdgcn_fdot2)
#define HAS_FDOT2 1
#endif
#endif

typedef _Float16 half2r __attribute__((ext_vector_type(2)));

// dot2: c += a.lo*b.lo + a.hi*b.hi  (f16 pairs, f32 accumulate)
__device__ __forceinline__ float dot2acc(unsigned a, unsigned b, float c) {
#ifdef HAS_FDOT2
  return __builtin_amdgcn_fdot2(__builtin_bit_cast(half2r, a),
                                __builtin_bit_cast(half2r, b), c, false);
#else
  const __half2 ha = *(const __half2*)&a;
  const __half2 hb = *(const __half2*)&b;
  return c + __low2float(ha) * __low2float(hb)
           + __high2float(ha) * __high2float(hb);
#endif
}

// ------- embed + hist fused, v3: W-in-VGPR, fp16 h output -------------
__global__ __launch_bounds__(256) void embed_hist_kernel(
    const float* __restrict__ feat, const float* __restrict__ W,
    const float* __restrict__ b, __half* __restrict__ h,
    const int* __restrict__ dst, int* __restrict__ deg) {
  __shared__ float sF[4][2][512];   // wave x buf x (4 rows * 128) = 16 KB
  const int lane = threadIdx.x & 63;
  const int wave = threadIdx.x >> 6;
  float Wreg[INF];
#pragma unroll
  for (int k = 0; k < INF; k++) Wreg[k] = W[k * HD + lane];
  const float bias = b[lane];
  const int nwaves = gridDim.x * 4;
  const int wid = blockIdx.x * 4 + wave;   // wave-uniform
  const int ngroups = NV / 4;              // 12500 exactly

  int buf = 0;
  int g = wid;
  if (g < ngroups) {
    const float4* gp = (const float4*)(feat + (size_t)g * 512);
    const float4 a0 = gp[lane];
    const float4 a1 = gp[lane + 64];
    ((float4*)sF[wave][0])[lane] = a0;
    ((float4*)sF[wave][0])[lane + 64] = a1;
  }
  for (; g < ngroups; g += nwaves) {
    const int gn = g + nwaves;
    float4 b0, b1;
    if (gn < ngroups) {                    // wave-uniform guard
      const float4* gp = (const float4*)(feat + (size_t)gn * 512);
      b0 = gp[lane];
      b1 = gp[lane + 64];
    }
    float acc0 = bias, acc1 = bias, acc2 = bias, acc3 = bias;
    const float4* F = (const float4*)sF[wave][buf];
#pragma unroll
    for (int k4 = 0; k4 < 32; k4++) {
      const float4 x0 = F[k4];
      const float4 x1 = F[k4 + 32];
      const float4 x2 = F[k4 + 64];
      const float4 x3 = F[k4 + 96];
      const float w0 = Wreg[4 * k4 + 0];
      const float w1 = Wreg[4 * k4 + 1];
      const float w2 = Wreg[4 * k4 + 2];
      const float w3 = Wreg[4 * k4 + 3];
      acc0 = fmaf(x0.x, w0, acc0); acc0 = fmaf(x0.y, w1, acc0);
      acc0 = fmaf(x0.z, w2, acc0); acc0 = fmaf(x0.w, w3, acc0);
      acc1 = fmaf(x1.x, w0, acc1); acc1 = fmaf(x1.y, w1, acc1);
      acc1 = fmaf(x1.z, w2, acc1); acc1 = fmaf(x1.w, w3, acc1);
      acc2 = fmaf(x2.x, w0, acc2); acc2 = fmaf(x2.y, w1, acc2);
      acc2 = fmaf(x2.z, w2, acc2); acc2 = fmaf(x2.w, w3, acc2);
      acc3 = fmaf(x3.x, w0, acc3); acc3 = fmaf(x3.y, w1, acc3);
      acc3 = fmaf(x3.z, w2, acc3); acc3 = fmaf(x3.w, w3, acc3);
    }
    __half* hpo = h + (size_t)g * 256 + lane;   // 4 coalesced 128B stores
    hpo[0]   = __float2half_rn(acc0);
    hpo[64]  = __float2half_rn(acc1);
    hpo[128] = __float2half_rn(acc2);
    hpo[192] = __float2half_rn(acc3);
    if (gn < ngroups) {
      ((float4*)sF[wave][buf ^ 1])[lane] = b0;
      ((float4*)sF[wave][buf ^ 1])[lane + 64] = b1;
      buf ^= 1;
    }
  }
  for (int e = blockIdx.x * 256 + threadIdx.x; e < EV; e += gridDim.x * 256)
    atomicAdd(&deg[dst[e]], 1);
}

// ------- parallel scan, pass 1 ----------------------------------------
__global__ __launch_bounds__(1024) void scan_part_kernel(
    const int* __restrict__ deg, int* __restrict__ off,
    int* __restrict__ bsum) {
  __shared__ int wsum[16];
  const int tid = threadIdx.x;
  const int lane = tid & 63;
  const int w = tid >> 6;
  const int i = blockIdx.x * 1024 + tid;
  const int v = (i < NV) ? deg[i] : 0;
  int s = v;
#pragma unroll
  for (int ofs = 1; ofs < 64; ofs <<= 1) {
    int x = __shfl_up(s, ofs, 64);
    if (lane >= ofs) s += x;
  }
  if (lane == 63) wsum[w] = s;
  __syncthreads();
  if (w == 0) {
    int t2 = (lane < 16) ? wsum[lane] : 0;
#pragma unroll
    for (int ofs = 1; ofs < 16; ofs <<= 1) {
      int x = __shfl_up(t2, ofs, 64);
      if (lane >= ofs) t2 += x;
    }
    if (lane < 16) wsum[lane] = t2;
  }
  __syncthreads();
  const int base = (w > 0) ? wsum[w - 1] : 0;
  if (i < NV) off[i] = base + s - v;
  if (tid == 0) bsum[blockIdx.x] = wsum[15];
}

// ------- parallel scan, pass 2 ----------------------------------------
__global__ __launch_bounds__(1024) void scan_fix_kernel(
    const int* __restrict__ bsum, int* __restrict__ off,
    int* __restrict__ cursor) {
  __shared__ int sbase, stot;
  const int tid = threadIdx.x;
  const int b = blockIdx.x;
  if (tid == 0) {
    int acc = 0, tot = 0;
    for (int j = 0; j < NB; j++) {
      const int x = bsum[j];
      if (j < b) acc += x;
      tot += x;
    }
    sbase = acc;
    stot = tot;
  }
  __syncthreads();
  const int i = b * 1024 + tid;
  if (i < NV) {
    const int o = off[i] + sbase;
    off[i] = o;
    cursor[i] = o;
  }
  if (b == NB - 1 && tid == 0) off[NV] = stot;
}

// ------- CSR perm -----------------------------------------------------
__global__ __launch_bounds__(256) void perm_kernel(
    const int* __restrict__ src, const int* __restrict__ dst,
    int* __restrict__ cursor, int* __restrict__ gsrc) {
  const int e = blockIdx.x * 256 + threadIdx.x;
  if (e < EV) {
    const int pos = atomicAdd(&cursor[dst[e]], 1);
    gsrc[pos] = src[e];
  }
}

// ------- fused aggregate + combine, v7 (unchanged from r7) ------------
__global__ __launch_bounds__(256) void aggcomb_kernel(
    const __half* __restrict__ hin, __half* __restrict__ hout,
    const int* __restrict__ gsrc, const int* __restrict__ off,
    const float* __restrict__ wconv, const float* __restrict__ cb,
    const float* __restrict__ gamma, const float* __restrict__ beta,
    const float* __restrict__ mean, const float* __restrict__ var) {
  __shared__ float sS1[4][4][HD];   // wave x slot x row  (4 KB)
  __shared__ float sH[4][4][HD];    // wave x slot x own-h (4 KB)
  const int wave = threadIdx.x >> 6;
  const int lane = threadIdx.x & 63;
  const int sub = lane >> 4;   // node slot 0..3
  const int q = lane & 15;     // uint2 slot within fp16 row
  const int f = lane;          // output feature in combine phase
  float Wsr[HD], Wdr[HD];
#pragma unroll
  for (int k = 0; k < HD; k++) Wsr[k] = wconv[k * HD + f];
#pragma unroll
  for (int k = 0; k < HD; k++) Wdr[k] = wconv[(HD + k) * HD + f];
  const float cbf = cb[f];
  const float gf = gamma[f];
  const float btf = beta[f];
  const float mf = mean[f];
  const float inv = rsqrtf(var[f] + 1e-3f);
  const uint2* hp = (const uint2*)hin;   // 4 halves/lane, 16 lanes/row
  const int wid = blockIdx.x * 4 + wave;
  const int nw = gridDim.x * 4;
  const int ngroups = NV / 4;            // 12500 exactly
  for (int g = wid; g < ngroups; g += nw) {
    const int n0 = g * 4;
    const int n = n0 + sub;              // this slot's node
    const int j0 = off[n];
    const int deg = off[n + 1] - j0;
    int dm = deg;                        // wave-max degree
    dm = max(dm, __shfl_xor(dm, 16, 64));
    dm = max(dm, __shfl_xor(dm, 32, 64));
    const uint2 hrv = hp[(size_t)n * 16 + q];     // own row fragment
    float4 acc = make_float4(0.f, 0.f, 0.f, 0.f);
    for (int base = 0; base < dm; base += 16) {
      const int e = base + q;
      const int eid = (e < deg) ? gsrc[j0 + e] : -1;
#pragma unroll
      for (int i = 0; i < 16; i++) {
        const int a = __shfl(eid, (sub << 4) | i, 64);
        const uint2 v = hp[(size_t)max(a, 0) * 16 + q];
        const __half2 p0 = *(const __half2*)&v.x;
        const __half2 p1 = *(const __half2*)&v.y;
        const float msk = (a >= 0) ? 1.f : 0.f;
        acc.x = fmaf(__low2float(p0),  msk, acc.x);
        acc.y = fmaf(__high2float(p0), msk, acc.y);
        acc.z = fmaf(__low2float(p1),  msk, acc.z);
        acc.w = fmaf(__high2float(p1), msk, acc.w);
      }
    }
    // hand-off via wave-private LDS (in-order DS pipe; no barrier)
    {
      const __half2 p0 = *(const __half2*)&hrv.x;
      const __half2 p1 = *(const __half2*)&hrv.y;
      const float4 hrowf = make_float4(__low2float(p0), __high2float(p0),
                                       __low2float(p1), __high2float(p1));
      ((float4*)sS1[wave][sub])[q] = acc;
      ((float4*)sH[wave][sub])[q] = hrowf;
    }
#pragma unroll
    for (int m4 = 0; m4 < 4; m4++) {
      const float4* s1p = (const float4*)sS1[wave][m4];
      const float4* hq = (const float4*)sH[wave][m4];
      float a1a = 0.f, a1b = 0.f, a2a = 0.f, a2b = 0.f;
#pragma unroll
      for (int k4 = 0; k4 < 16; k4++) {
        const float4 sv = s1p[k4];       // uniform addr -> broadcast
        const float4 hv = hq[k4];
        a1a = fmaf(sv.x, Wsr[4 * k4 + 0], a1a);
        a1b = fmaf(sv.y, Wsr[4 * k4 + 1], a1b);
        a1a = fmaf(sv.z, Wsr[4 * k4 + 2], a1a);
        a1b = fmaf(sv.w, Wsr[4 * k4 + 3], a1b);
        a2a = fmaf(hv.x, Wdr[4 * k4 + 0], a2a);
        a2b = fmaf(hv.y, Wdr[4 * k4 + 1], a2b);
        a2a = fmaf(hv.z, Wdr[4 * k4 + 2], a2a);
        a2b = fmaf(hv.w, Wdr[4 * k4 + 3], a2b);
      }
      const float a1 = a1a + a1b;
      const float a2 = a2a + a2b;
      const float hvf = sH[wave][m4][f];          // conflict-free b32
      const float d = (float)__shfl(deg, m4 << 4, 64);
      const float agg = a1 + d * a2 + d * cbf;
      const float sig = 1.f / (1.f + __expf(-agg));
      const float sp = fmaxf(hvf, 0.f) + log1pf(__expf(-fabsf(hvf)));
      float x = sig + sp;
      x = gf * (x - mf) * inv + btf;
      hout[(size_t)(n0 + m4) * HD + f] = __float2half_rn(fmaxf(x, 0.f));
    }
  }
}

// ------- scores v2: dot2 math + joint reduce-scatter ------------------
// 8 lanes/edge (q owns 8 features = one uint4 of fp16). aw = h_src*w
// packed fp16 (pk_mul); each score fragment = 4 chained v_dot2_f32_f16.
// All 6 scores reduced JOINTLY over the 8 lanes via recursive halving
// (7 shfl + 7 adds vs 6 separate butterflies = 18+18); lane q ends with
// score index q (0=pos, 1..5=neg) and writes it directly.
__global__ __launch_bounds__(256) void score_kernel(
    const __half* __restrict__ hh, const int* __restrict__ src,
    const int* __restrict__ dst, const int* __restrict__ neg_dst,
    const float* __restrict__ wrel, float* __restrict__ out) {
  const int tid = blockIdx.x * 256 + threadIdx.x;
  const int e = tid >> 3;
  const int q = tid & 7;
  if (e >= EV) return;
  const float4 w0 = ((const float4*)wrel)[2 * q];
  const float4 w1 = ((const float4*)wrel)[2 * q + 1];
  const __half2 wh0 = __floats2half2_rn(w0.x, w0.y);
  const __half2 wh1 = __floats2half2_rn(w0.z, w0.w);
  const __half2 wh2 = __floats2half2_rn(w1.x, w1.y);
  const __half2 wh3 = __floats2half2_rn(w1.z, w1.w);
  const int s = src[e];
  const int d = dst[e];
  int nd[KNEG];
#pragma unroll
  for (int r = 0; r < KNEG; r++) nd[r] = neg_dst[e * KNEG + r];

  const uint4* hp = (const uint4*)hh;
  const uint4 sv = hp[(size_t)s * 8 + q];
  const uint4 dv = hp[(size_t)d * 8 + q];
  uint4 nv[KNEG];
#pragma unroll
  for (int r = 0; r < KNEG; r++) nv[r] = hp[(size_t)nd[r] * 8 + q];

  // aw = h_src * w in fp16 pairs (v_pk_mul_f16)
  const unsigned au0 = __builtin_bit_cast(unsigned,
      __hmul2(*(const __half2*)&sv.x, wh0));
  const unsigned au1 = __builtin_bit_cast(unsigned,
      __hmul2(*(const __half2*)&sv.y, wh1));
  const unsigned au2 = __builtin_bit_cast(unsigned,
      __hmul2(*(const __half2*)&sv.z, wh2));
  const unsigned au3 = __builtin_bit_cast(unsigned,
      __hmul2(*(const __half2*)&sv.w, wh3));

  float v0 = dot2acc(au3, dv.w,
             dot2acc(au2, dv.z,
             dot2acc(au1, dv.y,
             dot2acc(au0, dv.x, 0.f))));
  float v1, v2, v3, v4, v5;
  {
    float pn[KNEG];
#pragma unroll
    for (int r = 0; r < KNEG; r++) {
      pn[r] = dot2acc(au3, nv[r].w,
              dot2acc(au2, nv[r].z,
              dot2acc(au1, nv[r].y,
              dot2acc(au0, nv[r].x, 0.f))));
    }
    v1 = pn[0]; v2 = pn[1]; v3 = pn[2]; v4 = pn[3]; v5 = pn[4];
  }
  // joint reduce-scatter over the 8 lanes: lane q ends with score q
  {
    const bool hi = (q & 4) != 0;
    float t0 = hi ? v0 : v4, t1 = hi ? v1 : v5;
    float t2 = hi ? v2 : 0.f, t3 = hi ? v3 : 0.f;
    t0 = __shfl_xor(t0, 4, 64); t1 = __shfl_xor(t1, 4, 64);
    t2 = __shfl_xor(t2, 4, 64); t3 = __shfl_xor(t3, 4, 64);
    v0 = (hi ? v4 : v0) + t0;
    v1 = (hi ? v5 : v1) + t1;
    v2 = (hi ? 0.f : v2) + t2;
    v3 = (hi ? 0.f : v3) + t3;
  }
  {
    const bool hi = (q & 2) != 0;
    float t0 = hi ? v0 : v2, t1 = hi ? v1 : v3;
    t0 = __shfl_xor(t0, 2, 64); t1 = __shfl_xor(t1, 2, 64);
    v0 = (hi ? v2 : v0) + t0;
    v1 = (hi ? v3 : v1) + t1;
  }
  {
    const bool hi = (q & 1) != 0;
    float t0 = hi ? v0 : v1;
    t0 = __shfl_xor(t0, 1, 64);
    v0 = (hi ? v1 : v0) + t0;
  }
  if (q == 0) out[e] = v0;
  else if (q <= KNEG) out[(size_t)EV + (size_t)e * KNEG + (q - 1)] = v0;
}

extern "C" void kernel_launch(void* const* d_in, const int* in_sizes, int n_in,
                              void* d_out, int out_size, void* d_ws, size_t ws_size,
                              hipStream_t stream) {
  const float* node_feat = (const float*)d_in[0];
  const float* emb_w     = (const float*)d_in[1];
  const float* emb_b     = (const float*)d_in[2];
  const float* conv_w    = (const float*)d_in[3];
  const float* conv_b    = (const float*)d_in[4];
  const float* bn_gamma  = (const float*)d_in[5];
  const float* bn_beta   = (const float*)d_in[6];
  const float* bn_mean   = (const float*)d_in[7];
  const float* bn_var    = (const float*)d_in[8];
  const float* w_rel     = (const float*)d_in[9];
  const int*   src       = (const int*)d_in[10];
  const int*   dst       = (const int*)d_in[11];
  const int*   neg_dst   = (const int*)d_in[12];
  float* out = (float*)d_out;

  // ws layout (fp16 ping-pong): H0 | H1 | off (N+1) | gsrc (E) | bsum
  __half* H0 = (__half*)d_ws;                    // NV x HD fp16
  __half* H1 = H0 + (size_t)NV * HD;
  int*   off  = (int*)(H1 + (size_t)NV * HD);
  int*   gsrc = off + (NV + 1);
  int*   bsum = gsrc + EV;
  int*   deg    = (int*)H1;            // alias: H1[0 .. NV)
  int*   cursor = ((int*)H1) + NV;     // alias: H1[NV .. 2NV)

  hipMemsetAsync(deg, 0, (size_t)NV * sizeof(int), stream);
  embed_hist_kernel<<<1024, 256, 0, stream>>>(node_feat, emb_w, emb_b, H0,
                                              dst, deg);
  scan_part_kernel<<<NB, 1024, 0, stream>>>(deg, off, bsum);
  scan_fix_kernel<<<NB, 1024, 0, stream>>>(bsum, off, cursor);
  perm_kernel<<<(EV + 255) / 256, 256, 0, stream>>>(src, dst, cursor, gsrc);

  // layer 0: H0 -> H1 ; layer 1: H1 -> H0  (ping-pong)
  aggcomb_kernel<<<512, 256, 0, stream>>>(
      H0, H1, gsrc, off, conv_w, conv_b,
      bn_gamma, bn_beta, bn_mean, bn_var);
  aggcomb_kernel<<<512, 256, 0, stream>>>(
      H1, H0, gsrc, off, conv_w + 2 * HD * HD, conv_b + HD,
      bn_gamma + HD, bn_beta + HD, bn_mean + HD, bn_var + HD);

  score_kernel<<<((size_t)EV * 8 + 255) / 256, 256, 0, stream>>>(
      H0, src, dst, neg_dst, w_rel, out);
}

// Round 9
// 309.928 us; speedup vs baseline: 2.7189x; 1.0566x over previous
//
#include <hip/hip_runtime.h>
#include <hip/hip_fp16.h>

#define NV 50000
#define EV 800000
#define INF 128
#define HD 64
#define KNEG 5
#define NB ((NV + 1023) / 1024)   // 49 scan blocks

#if defined(__has_builtin)
#if __has_builtin(__builtin_amdgcn_fdot2)
#define HAS_FDOT2 1
#endif
#endif

typedef _Float16 half2r __attribute__((ext_vector_type(2)));

// dot2: c += a.lo*b.lo + a.hi*b.hi  (f16 pairs, f32 accumulate)
__device__ __forceinline__ float dot2acc(unsigned a, unsigned b, float c) {
#ifdef HAS_FDOT2
  return __builtin_amdgcn_fdot2(__builtin_bit_cast(half2r, a),
                                __builtin_bit_cast(half2r, b), c, false);
#else
  const __half2 ha = *(const __half2*)&a;
  const __half2 hb = *(const __half2*)&b;
  return c + __low2float(ha) * __low2float(hb)
           + __high2float(ha) * __high2float(hb);
#endif
}

// ------- embed + hist fused, v4: hist also records edge rank ----------
// h = feat @ W + b stored fp16. Hist atomicAdd's RETURN VALUE is the
// edge's rank within its dst segment -> stored coalesced (u16). This
// lets perm_kernel drop its 800K cursor atomics entirely.
__global__ __launch_bounds__(256) void embed_hist_kernel(
    const float* __restrict__ feat, const float* __restrict__ W,
    const float* __restrict__ b, __half* __restrict__ h,
    const int* __restrict__ dst, int* __restrict__ deg,
    unsigned short* __restrict__ rank) {
  __shared__ float sF[4][2][512];   // wave x buf x (4 rows * 128) = 16 KB
  const int lane = threadIdx.x & 63;
  const int wave = threadIdx.x >> 6;
  float Wreg[INF];
#pragma unroll
  for (int k = 0; k < INF; k++) Wreg[k] = W[k * HD + lane];
  const float bias = b[lane];
  const int nwaves = gridDim.x * 4;
  const int wid = blockIdx.x * 4 + wave;   // wave-uniform
  const int ngroups = NV / 4;              // 12500 exactly

  int buf = 0;
  int g = wid;
  if (g < ngroups) {
    const float4* gp = (const float4*)(feat + (size_t)g * 512);
    const float4 a0 = gp[lane];
    const float4 a1 = gp[lane + 64];
    ((float4*)sF[wave][0])[lane] = a0;
    ((float4*)sF[wave][0])[lane + 64] = a1;
  }
  for (; g < ngroups; g += nwaves) {
    const int gn = g + nwaves;
    float4 b0, b1;
    if (gn < ngroups) {                    // wave-uniform guard
      const float4* gp = (const float4*)(feat + (size_t)gn * 512);
      b0 = gp[lane];
      b1 = gp[lane + 64];
    }
    float acc0 = bias, acc1 = bias, acc2 = bias, acc3 = bias;
    const float4* F = (const float4*)sF[wave][buf];
#pragma unroll
    for (int k4 = 0; k4 < 32; k4++) {
      const float4 x0 = F[k4];
      const float4 x1 = F[k4 + 32];
      const float4 x2 = F[k4 + 64];
      const float4 x3 = F[k4 + 96];
      const float w0 = Wreg[4 * k4 + 0];
      const float w1 = Wreg[4 * k4 + 1];
      const float w2 = Wreg[4 * k4 + 2];
      const float w3 = Wreg[4 * k4 + 3];
      acc0 = fmaf(x0.x, w0, acc0); acc0 = fmaf(x0.y, w1, acc0);
      acc0 = fmaf(x0.z, w2, acc0); acc0 = fmaf(x0.w, w3, acc0);
      acc1 = fmaf(x1.x, w0, acc1); acc1 = fmaf(x1.y, w1, acc1);
      acc1 = fmaf(x1.z, w2, acc1); acc1 = fmaf(x1.w, w3, acc1);
      acc2 = fmaf(x2.x, w0, acc2); acc2 = fmaf(x2.y, w1, acc2);
      acc2 = fmaf(x2.z, w2, acc2); acc2 = fmaf(x2.w, w3, acc2);
      acc3 = fmaf(x3.x, w0, acc3); acc3 = fmaf(x3.y, w1, acc3);
      acc3 = fmaf(x3.z, w2, acc3); acc3 = fmaf(x3.w, w3, acc3);
    }
    __half* hpo = h + (size_t)g * 256 + lane;   // 4 coalesced 128B stores
    hpo[0]   = __float2half_rn(acc0);
    hpo[64]  = __float2half_rn(acc1);
    hpo[128] = __float2half_rn(acc2);
    hpo[192] = __float2half_rn(acc3);
    if (gn < ngroups) {
      ((float4*)sF[wave][buf ^ 1])[lane] = b0;
      ((float4*)sF[wave][buf ^ 1])[lane + 64] = b1;
      buf ^= 1;
    }
  }
  for (int e = blockIdx.x * 256 + threadIdx.x; e < EV; e += gridDim.x * 256) {
    const int r = atomicAdd(&deg[dst[e]], 1);
    rank[e] = (unsigned short)r;               // coalesced u16 store
  }
}

// ------- parallel scan, pass 1 ----------------------------------------
__global__ __launch_bounds__(1024) void scan_part_kernel(
    const int* __restrict__ deg, int* __restrict__ off,
    int* __restrict__ bsum) {
  __shared__ int wsum[16];
  const int tid = threadIdx.x;
  const int lane = tid & 63;
  const int w = tid >> 6;
  const int i = blockIdx.x * 1024 + tid;
  const int v = (i < NV) ? deg[i] : 0;
  int s = v;
#pragma unroll
  for (int ofs = 1; ofs < 64; ofs <<= 1) {
    int x = __shfl_up(s, ofs, 64);
    if (lane >= ofs) s += x;
  }
  if (lane == 63) wsum[w] = s;
  __syncthreads();
  if (w == 0) {
    int t2 = (lane < 16) ? wsum[lane] : 0;
#pragma unroll
    for (int ofs = 1; ofs < 16; ofs <<= 1) {
      int x = __shfl_up(t2, ofs, 64);
      if (lane >= ofs) t2 += x;
    }
    if (lane < 16) wsum[lane] = t2;
  }
  __syncthreads();
  const int base = (w > 0) ? wsum[w - 1] : 0;
  if (i < NV) off[i] = base + s - v;
  if (tid == 0) bsum[blockIdx.x] = wsum[15];
}

// ------- parallel scan, pass 2 (cursor removed) -----------------------
__global__ __launch_bounds__(1024) void scan_fix_kernel(
    const int* __restrict__ bsum, int* __restrict__ off) {
  __shared__ int sbase, stot;
  const int tid = threadIdx.x;
  const int b = blockIdx.x;
  if (tid == 0) {
    int acc = 0, tot = 0;
    for (int j = 0; j < NB; j++) {
      const int x = bsum[j];
      if (j < b) acc += x;
      tot += x;
    }
    sbase = acc;
    stot = tot;
  }
  __syncthreads();
  const int i = b * 1024 + tid;
  if (i < NV) off[i] += sbase;
  if (b == NB - 1 && tid == 0) off[NV] = stot;
}

// ------- CSR perm, v2: no atomics, u16 payload, nt scatter ------------
// pos = off[dst[e]] + rank[e] (rank captured by the hist atomic).
// off is a 200 KB L2-resident table; the only scatter is the u16
// nontemporal store (no write-allocate -> avoids 64B line write-amp).
__global__ __launch_bounds__(256) void perm_kernel(
    const int* __restrict__ src, const int* __restrict__ dst,
    const unsigned short* __restrict__ rank, const int* __restrict__ off,
    unsigned short* __restrict__ gsrc) {
  const int e = blockIdx.x * 256 + threadIdx.x;
  if (e < EV) {
    const int pos = off[dst[e]] + (int)rank[e];
    __builtin_nontemporal_store((unsigned short)src[e], &gsrc[pos]);
  }
}

// ------- fused aggregate + combine, v7b: u16 gsrc ---------------------
__global__ __launch_bounds__(256) void aggcomb_kernel(
    const __half* __restrict__ hin, __half* __restrict__ hout,
    const unsigned short* __restrict__ gsrc, const int* __restrict__ off,
    const float* __restrict__ wconv, const float* __restrict__ cb,
    const float* __restrict__ gamma, const float* __restrict__ beta,
    const float* __restrict__ mean, const float* __restrict__ var) {
  __shared__ float sS1[4][4][HD];   // wave x slot x row  (4 KB)
  __shared__ float sH[4][4][HD];    // wave x slot x own-h (4 KB)
  const int wave = threadIdx.x >> 6;
  const int lane = threadIdx.x & 63;
  const int sub = lane >> 4;   // node slot 0..3
  const int q = lane & 15;     // uint2 slot within fp16 row
  const int f = lane;          // output feature in combine phase
  float Wsr[HD], Wdr[HD];
#pragma unroll
  for (int k = 0; k < HD; k++) Wsr[k] = wconv[k * HD + f];
#pragma unroll
  for (int k = 0; k < HD; k++) Wdr[k] = wconv[(HD + k) * HD + f];
  const float cbf = cb[f];
  const float gf = gamma[f];
  const float btf = beta[f];
  const float mf = mean[f];
  const float inv = rsqrtf(var[f] + 1e-3f);
  const uint2* hp = (const uint2*)hin;   // 4 halves/lane, 16 lanes/row
  const int wid = blockIdx.x * 4 + wave;
  const int nw = gridDim.x * 4;
  const int ngroups = NV / 4;            // 12500 exactly
  for (int g = wid; g < ngroups; g += nw) {
    const int n0 = g * 4;
    const int n = n0 + sub;              // this slot's node
    const int j0 = off[n];
    const int deg = off[n + 1] - j0;
    int dm = deg;                        // wave-max degree
    dm = max(dm, __shfl_xor(dm, 16, 64));
    dm = max(dm, __shfl_xor(dm, 32, 64));
    const uint2 hrv = hp[(size_t)n * 16 + q];     // own row fragment
    float4 acc = make_float4(0.f, 0.f, 0.f, 0.f);
    for (int base = 0; base < dm; base += 16) {
      const int e = base + q;
      const int eid = (e < deg) ? (int)gsrc[j0 + e] : -1;
#pragma unroll
      for (int i = 0; i < 16; i++) {
        const int a = __shfl(eid, (sub << 4) | i, 64);
        const uint2 v = hp[(size_t)max(a, 0) * 16 + q];
        const __half2 p0 = *(const __half2*)&v.x;
        const __half2 p1 = *(const __half2*)&v.y;
        const float msk = (a >= 0) ? 1.f : 0.f;
        acc.x = fmaf(__low2float(p0),  msk, acc.x);
        acc.y = fmaf(__high2float(p0), msk, acc.y);
        acc.z = fmaf(__low2float(p1),  msk, acc.z);
        acc.w = fmaf(__high2float(p1), msk, acc.w);
      }
    }
    // hand-off via wave-private LDS (in-order DS pipe; no barrier)
    {
      const __half2 p0 = *(const __half2*)&hrv.x;
      const __half2 p1 = *(const __half2*)&hrv.y;
      const float4 hrowf = make_float4(__low2float(p0), __high2float(p0),
                                       __low2float(p1), __high2float(p1));
      ((float4*)sS1[wave][sub])[q] = acc;
      ((float4*)sH[wave][sub])[q] = hrowf;
    }
#pragma unroll
    for (int m4 = 0; m4 < 4; m4++) {
      const float4* s1p = (const float4*)sS1[wave][m4];
      const float4* hq = (const float4*)sH[wave][m4];
      float a1a = 0.f, a1b = 0.f, a2a = 0.f, a2b = 0.f;
#pragma unroll
      for (int k4 = 0; k4 < 16; k4++) {
        const float4 sv = s1p[k4];       // uniform addr -> broadcast
        const float4 hv = hq[k4];
        a1a = fmaf(sv.x, Wsr[4 * k4 + 0], a1a);
        a1b = fmaf(sv.y, Wsr[4 * k4 + 1], a1b);
        a1a = fmaf(sv.z, Wsr[4 * k4 + 2], a1a);
        a1b = fmaf(sv.w, Wsr[4 * k4 + 3], a1b);
        a2a = fmaf(hv.x, Wdr[4 * k4 + 0], a2a);
        a2b = fmaf(hv.y, Wdr[4 * k4 + 1], a2b);
        a2a = fmaf(hv.z, Wdr[4 * k4 + 2], a2a);
        a2b = fmaf(hv.w, Wdr[4 * k4 + 3], a2b);
      }
      const float a1 = a1a + a1b;
      const float a2 = a2a + a2b;
      const float hvf = sH[wave][m4][f];          // conflict-free b32
      const float d = (float)__shfl(deg, m4 << 4, 64);
      const float agg = a1 + d * a2 + d * cbf;
      const float sig = 1.f / (1.f + __expf(-agg));
      const float sp = fmaxf(hvf, 0.f) + log1pf(__expf(-fabsf(hvf)));
      float x = sig + sp;
      x = gf * (x - mf) * inv + btf;
      hout[(size_t)(n0 + m4) * HD + f] = __float2half_rn(fmaxf(x, 0.f));
    }
  }
}

// ------- scores v2: dot2 math + joint reduce-scatter ------------------
__global__ __launch_bounds__(256) void score_kernel(
    const __half* __restrict__ hh, const int* __restrict__ src,
    const int* __restrict__ dst, const int* __restrict__ neg_dst,
    const float* __restrict__ wrel, float* __restrict__ out) {
  const int tid = blockIdx.x * 256 + threadIdx.x;
  const int e = tid >> 3;
  const int q = tid & 7;
  if (e >= EV) return;
  const float4 w0 = ((const float4*)wrel)[2 * q];
  const float4 w1 = ((const float4*)wrel)[2 * q + 1];
  const __half2 wh0 = __floats2half2_rn(w0.x, w0.y);
  const __half2 wh1 = __floats2half2_rn(w0.z, w0.w);
  const __half2 wh2 = __floats2half2_rn(w1.x, w1.y);
  const __half2 wh3 = __floats2half2_rn(w1.z, w1.w);
  const int s = src[e];
  const int d = dst[e];
  int nd[KNEG];
#pragma unroll
  for (int r = 0; r < KNEG; r++) nd[r] = neg_dst[e * KNEG + r];

  const uint4* hp = (const uint4*)hh;
  const uint4 sv = hp[(size_t)s * 8 + q];
  const uint4 dv = hp[(size_t)d * 8 + q];
  uint4 nv[KNEG];
#pragma unroll
  for (int r = 0; r < KNEG; r++) nv[r] = hp[(size_t)nd[r] * 8 + q];

  // aw = h_src * w in fp16 pairs (v_pk_mul_f16)
  const unsigned au0 = __builtin_bit_cast(unsigned,
      __hmul2(*(const __half2*)&sv.x, wh0));
  const unsigned au1 = __builtin_bit_cast(unsigned,
      __hmul2(*(const __half2*)&sv.y, wh1));
  const unsigned au2 = __builtin_bit_cast(unsigned,
      __hmul2(*(const __half2*)&sv.z, wh2));
  const unsigned au3 = __builtin_bit_cast(unsigned,
      __hmul2(*(const __half2*)&sv.w, wh3));

  float v0 = dot2acc(au3, dv.w,
             dot2acc(au2, dv.z,
             dot2acc(au1, dv.y,
             dot2acc(au0, dv.x, 0.f))));
  float v1, v2, v3, v4, v5;
  {
    float pn[KNEG];
#pragma unroll
    for (int r = 0; r < KNEG; r++) {
      pn[r] = dot2acc(au3, nv[r].w,
              dot2acc(au2, nv[r].z,
              dot2acc(au1, nv[r].y,
              dot2acc(au0, nv[r].x, 0.f))));
    }
    v1 = pn[0]; v2 = pn[1]; v3 = pn[2]; v4 = pn[3]; v5 = pn[4];
  }
  // joint reduce-scatter over the 8 lanes: lane q ends with score q
  {
    const bool hi = (q & 4) != 0;
    float t0 = hi ? v0 : v4, t1 = hi ? v1 : v5;
    float t2 = hi ? v2 : 0.f, t3 = hi ? v3 : 0.f;
    t0 = __shfl_xor(t0, 4, 64); t1 = __shfl_xor(t1, 4, 64);
    t2 = __shfl_xor(t2, 4, 64); t3 = __shfl_xor(t3, 4, 64);
    v0 = (hi ? v4 : v0) + t0;
    v1 = (hi ? v5 : v1) + t1;
    v2 = (hi ? 0.f : v2) + t2;
    v3 = (hi ? 0.f : v3) + t3;
  }
  {
    const bool hi = (q & 2) != 0;
    float t0 = hi ? v0 : v2, t1 = hi ? v1 : v3;
    t0 = __shfl_xor(t0, 2, 64); t1 = __shfl_xor(t1, 2, 64);
    v0 = (hi ? v2 : v0) + t0;
    v1 = (hi ? v3 : v1) + t1;
  }
  {
    const bool hi = (q & 1) != 0;
    float t0 = hi ? v0 : v1;
    t0 = __shfl_xor(t0, 1, 64);
    v0 = (hi ? v1 : v0) + t0;
  }
  if (q == 0) out[e] = v0;
  else if (q <= KNEG) out[(size_t)EV + (size_t)e * KNEG + (q - 1)] = v0;
}

extern "C" void kernel_launch(void* const* d_in, const int* in_sizes, int n_in,
                              void* d_out, int out_size, void* d_ws, size_t ws_size,
                              hipStream_t stream) {
  const float* node_feat = (const float*)d_in[0];
  const float* emb_w     = (const float*)d_in[1];
  const float* emb_b     = (const float*)d_in[2];
  const float* conv_w    = (const float*)d_in[3];
  const float* conv_b    = (const float*)d_in[4];
  const float* bn_gamma  = (const float*)d_in[5];
  const float* bn_beta   = (const float*)d_in[6];
  const float* bn_mean   = (const float*)d_in[7];
  const float* bn_var    = (const float*)d_in[8];
  const float* w_rel     = (const float*)d_in[9];
  const int*   src       = (const int*)d_in[10];
  const int*   dst       = (const int*)d_in[11];
  const int*   neg_dst   = (const int*)d_in[12];
  float* out = (float*)d_out;

  // ws layout: H0 | H1 | off (N+1) | gsrc (E u16) | bsum
  // deg + rank alias H1 (dead before layer-0 aggcomb writes H1).
  __half* H0 = (__half*)d_ws;                    // NV x HD fp16
  __half* H1 = H0 + (size_t)NV * HD;
  int*   off  = (int*)(H1 + (size_t)NV * HD);
  unsigned short* gsrc = (unsigned short*)(off + (NV + 1));
  int*   bsum = (int*)(gsrc + EV);
  int*   deg  = (int*)H1;                        // alias: H1 bytes [0, 200K)
  unsigned short* rank = (unsigned short*)(((int*)H1) + NV); // [200K, 1.8M)

  hipMemsetAsync(deg, 0, (size_t)NV * sizeof(int), stream);
  embed_hist_kernel<<<1024, 256, 0, stream>>>(node_feat, emb_w, emb_b, H0,
                                              dst, deg, rank);
  scan_part_kernel<<<NB, 1024, 0, stream>>>(deg, off, bsum);
  scan_fix_kernel<<<NB, 1024, 0, stream>>>(bsum, off);
  perm_kernel<<<(EV + 255) / 256, 256, 0, stream>>>(src, dst, rank, off, gsrc);

  // layer 0: H0 -> H1 ; layer 1: H1 -> H0  (ping-pong)
  aggcomb_kernel<<<512, 256, 0, stream>>>(
      H0, H1, gsrc, off, conv_w, conv_b,
      bn_gamma, bn_beta, bn_mean, bn_var);
  aggcomb_kernel<<<512, 256, 0, stream>>>(
      H1, H0, gsrc, off, conv_w + 2 * HD * HD, conv_b + HD,
      bn_gamma + HD, bn_beta + HD, bn_mean + HD, bn_var + HD);

  score_kernel<<<((size_t)EV * 8 + 255) / 256, 256, 0, stream>>>(
      H0, src, dst, neg_dst, w_rel, out);
}